// Round 1
// baseline (292.728 us; speedup 1.0000x reference)
//
#include <hip/hip_runtime.h>
#include <hip/hip_bf16.h>

#define BB  4
#define SS  127
#define DD  768
#define HH  12
#define HDl 64
#define NSl 128

// ---- workspace layout (floats) ----
constexpr int OFF_P   = 0;                          // B*S*D
constexpr int OFF_Q   = OFF_P  + BB*SS*DD;          // B*S*D
constexpr int OFF_V   = OFF_Q  + BB*SS*DD;          // B*NS*D
constexpr int OFF_QA  = OFF_V  + BB*NSl*DD;         // B*NS*H
constexpr int OFF_KA  = OFF_QA + BB*NSl*HH;         // B*NS*H
constexpr int OFF_W2A = OFF_KA + BB*NSl*HH;         // H*D
constexpr int OFF_WQA = OFF_W2A + HH*DD;            // H*D
constexpr int OFF_WKA = OFF_WQA + HH*DD;            // H*D
constexpr int OFF_BF  = OFF_WKA + HH*DD;            // 36: b2a[12], bqa[12], bka[12]
constexpr int OFF_EL  = OFF_BF + 36;                // B*NS*NS*H
constexpr int NPAIR   = BB * NSl * (NSl - 1);

// ---------------------------------------------------------------------------
// Fold kernel: W2A[h][c] = sum_d eW2[c, h*64+d]*ae[d]  (and same for Wq/aq, Wk/ak)
// plus 36 bias dots.
// ---------------------------------------------------------------------------
__global__ void fold_kernel(const float* __restrict__ Wq, const float* __restrict__ Wk,
                            const float* __restrict__ eW2,
                            const float* __restrict__ bq, const float* __restrict__ bk,
                            const float* __restrict__ eb2,
                            const float* __restrict__ aW,
                            float* __restrict__ W2A, float* __restrict__ WQA,
                            float* __restrict__ WKA, float* __restrict__ bfold) {
    int idx = blockIdx.x * 256 + threadIdx.x;
    const int total = 3 * HH * DD;
    if (idx < total) {
        int which = idx / (HH * DD);
        int r = idx % (HH * DD);
        int h = r / DD;
        int c = r % DD;
        const float* W = (which == 0) ? eW2 : (which == 1) ? Wq : Wk;
        const float* a = (which == 0) ? (aW + 2 * HDl) : (which == 1) ? aW : (aW + HDl);
        float s = 0.f;
        #pragma unroll 8
        for (int d = 0; d < HDl; ++d) s += W[c * DD + h * HDl + d] * a[d];
        float* Wdst = (which == 0) ? W2A : (which == 1) ? WQA : WKA;
        Wdst[h * DD + c] = s;
    } else if (idx < total + 36) {
        int r = idx - total;
        int which = r / HH, h = r % HH;
        const float* bb = (which == 0) ? eb2 : (which == 1) ? bq : bk;
        const float* a = (which == 0) ? (aW + 2 * HDl) : (which == 1) ? aW : (aW + HDl);
        float s = 0.f;
        for (int d = 0; d < HDl; ++d) s += bb[h * HDl + d] * a[d];
        bfold[r] = s;
    }
}

// ---------------------------------------------------------------------------
// Batched tiled f32 GEMM: z=0: P = desc @ eW1[:D]; z=1: Q = desc @ eW1[D:];
// z=2: v = nve @ Wv + bv.   C[M,768] = A[M,768] @ B[768,768]
// BM=BN=64, BK=16, 256 threads, 4x4 micro-tile.
// ---------------------------------------------------------------------------
__global__ void gemm3_kernel(const float* __restrict__ desc, const float* __restrict__ nve,
                             const float* __restrict__ eW1, const float* __restrict__ Wv,
                             const float* __restrict__ bv,
                             float* __restrict__ P, float* __restrict__ Qm,
                             float* __restrict__ V) {
    constexpr int BM = 64, BN = 64, BK = 16;
    const int z = blockIdx.z;
    const float* A    = (z == 2) ? nve : desc;
    const float* Bmat = (z == 0) ? eW1 : (z == 1) ? (eW1 + DD * DD) : Wv;
    float* C          = (z == 0) ? P : (z == 1) ? Qm : V;
    const int M       = (z == 2) ? (BB * NSl) : (BB * SS);
    const bool has_bias = (z == 2);

    __shared__ float As[BK][BM];
    __shared__ float Bs[BK][BN];

    const int brow = blockIdx.y * BM;
    const int bcol = blockIdx.x * BN;
    const int tid = threadIdx.x;
    const int tr = tid / (BN / 4);   // 0..15
    const int tc = tid % (BN / 4);   // 0..15

    float acc[4][4] = {};
    for (int k0 = 0; k0 < DD; k0 += BK) {
        for (int l = tid; l < BM * BK; l += 256) {
            int m = l / BK, kk = l % BK;
            int gm = brow + m;
            As[kk][m] = (gm < M) ? A[gm * DD + k0 + kk] : 0.f;
        }
        for (int l = tid; l < BK * BN; l += 256) {
            int kk = l / BN, n = l % BN;
            Bs[kk][n] = Bmat[(k0 + kk) * DD + bcol + n];
        }
        __syncthreads();
        #pragma unroll
        for (int kk = 0; kk < BK; ++kk) {
            float a[4], b[4];
            #pragma unroll
            for (int i = 0; i < 4; ++i) a[i] = As[kk][tr * 4 + i];
            #pragma unroll
            for (int j = 0; j < 4; ++j) b[j] = Bs[kk][tc * 4 + j];
            #pragma unroll
            for (int i = 0; i < 4; ++i)
                #pragma unroll
                for (int j = 0; j < 4; ++j) acc[i][j] += a[i] * b[j];
        }
        __syncthreads();
    }
    #pragma unroll
    for (int i = 0; i < 4; ++i) {
        int gm = brow + tr * 4 + i;
        if (gm >= M) continue;
        #pragma unroll
        for (int j = 0; j < 4; ++j) {
            int gn = bcol + tc * 4 + j;
            float v = acc[i][j];
            if (has_bias) v += bv[gn];
            C[gm * DD + gn] = v;
        }
    }
}

// ---------------------------------------------------------------------------
// qa[b,t,h] = nve[b,t,:]·WQA[h,:] + bqa[h]; ka analogous. One thread/output.
// ---------------------------------------------------------------------------
__global__ void qk_kernel(const float* __restrict__ nve,
                          const float* __restrict__ WQA, const float* __restrict__ WKA,
                          const float* __restrict__ bfold,
                          float* __restrict__ qa, float* __restrict__ ka) {
    int idx = blockIdx.x * 256 + threadIdx.x;
    if (idx >= BB * NSl * HH * 2) return;
    int which = idx & 1;
    int r = idx >> 1;
    int h = r % HH;
    int t = (r / HH) % NSl;
    int b = r / (HH * NSl);
    const float* W = which ? (WKA + h * DD) : (WQA + h * DD);
    const float* row = nve + (b * NSl + t) * DD;
    float s = bfold[12 + which * 12 + h];
    #pragma unroll 8
    for (int c = 0; c < DD; ++c) s += row[c] * W[c];
    (which ? ka : qa)[(b * NSl + t) * HH + h] = s;
}

// ---------------------------------------------------------------------------
// Pair kernel: one wave per (b, i in [0,NS), j in [1,NS)).
//   x = P[pi] + Q[j-1] + eb1  (pi = j-1 when i==0 else i-1)
//   y = relu(layernorm(x));  e_log[b,i,j,h] = y · W2A[h] + b2a[h]
// ---------------------------------------------------------------------------
__global__ void pair_kernel(const float* __restrict__ P, const float* __restrict__ Qm,
                            const float* __restrict__ eb1,
                            const float* __restrict__ ln_g, const float* __restrict__ ln_b,
                            const float* __restrict__ W2A, const float* __restrict__ bfold,
                            float* __restrict__ e_log) {
    int wid = (blockIdx.x * blockDim.x + threadIdx.x) >> 6;
    int lane = threadIdx.x & 63;
    if (wid >= NPAIR) return;
    int b = wid / (NSl * (NSl - 1));
    int rem = wid % (NSl * (NSl - 1));
    int i = rem / (NSl - 1);
    int j = 1 + rem % (NSl - 1);
    int pi = (i == 0) ? (j - 1) : (i - 1);

    const float* prow = P + (b * SS + pi) * DD;
    const float* qrow = Qm + (b * SS + (j - 1)) * DD;

    float x[12];
    float sum = 0.f, sumsq = 0.f;
    #pragma unroll
    for (int r = 0; r < 12; ++r) {
        int c = lane + 64 * r;
        float xv = prow[c] + qrow[c] + eb1[c];
        x[r] = xv;
        sum += xv;
        sumsq += xv * xv;
    }
    #pragma unroll
    for (int off = 32; off; off >>= 1) {
        sum += __shfl_xor(sum, off);
        sumsq += __shfl_xor(sumsq, off);
    }
    const float mean = sum * (1.f / DD);
    const float var = sumsq * (1.f / DD) - mean * mean;
    const float sc = rsqrtf(var + 1e-5f);

    float acc[12] = {};
    #pragma unroll
    for (int r = 0; r < 12; ++r) {
        int c = lane + 64 * r;
        float y = (x[r] - mean) * sc * ln_g[c] + ln_b[c];
        y = fmaxf(y, 0.f);
        #pragma unroll
        for (int h = 0; h < 12; ++h) acc[h] += y * W2A[h * DD + c];
    }
    #pragma unroll
    for (int h = 0; h < 12; ++h) {
        #pragma unroll
        for (int off = 32; off; off >>= 1) acc[h] += __shfl_xor(acc[h], off);
    }
    float outv = acc[0];
    #pragma unroll
    for (int h = 1; h < 12; ++h)
        if (lane == h) outv = acc[h];
    if (lane < HH)
        e_log[(((b * NSl + i) * NSl) + j) * HH + lane] = outv + bfold[lane];
}

// ---------------------------------------------------------------------------
// Softmax + context: one wave per (b,h,i). Assembles logits (+qa+ka+ab+mask
// bias), masks adj==0 (j=0; i>=1 && j==i), softmax, writes attn and
// context = sum_j p_j * v[b,j,h*64+d].
// ---------------------------------------------------------------------------
__global__ void softmax_ctx_kernel(const float* __restrict__ e_log,
                                   const float* __restrict__ qa, const float* __restrict__ ka,
                                   const float* __restrict__ mask_M, const float* __restrict__ ab,
                                   const float* __restrict__ V,
                                   float* __restrict__ out) {
    const int wid = blockIdx.x;
    const int lane = threadIdx.x;
    const int b = wid / (HH * NSl);
    const int rem = wid % (HH * NSl);
    const int h = rem / NSl;
    const int i = rem % NSl;

    __shared__ float plds[NSl];

    const float abv = ab[0];
    const float qv = qa[(b * NSl + i) * HH + h];

    float lg[2];
    bool valid[2];
    #pragma unroll
    for (int s = 0; s < 2; ++s) {
        int j = 1 + lane + 64 * s;
        bool v = (j < NSl) && !(i >= 1 && j == i);
        float l = -1e30f;
        if (v) {
            l = e_log[(((b * NSl + i) * NSl) + j) * HH + h] + qv
              + ka[(b * NSl + j) * HH + h] + abv;
            if (i >= 1) {
                float p = mask_M[((b * HH + h) * SS + (i - 1)) * SS + (j - 1)];
                p = fminf(fmaxf(p, 1e-6f), 1.0f - 1e-6f);
                l += logf(p) - logf(1.0f - p);
            }
        }
        lg[s] = l;
        valid[s] = v;
    }
    float m = fmaxf(lg[0], lg[1]);
    #pragma unroll
    for (int off = 32; off; off >>= 1) m = fmaxf(m, __shfl_xor(m, off));
    float e0 = valid[0] ? expf(lg[0] - m) : 0.f;
    float e1 = valid[1] ? expf(lg[1] - m) : 0.f;
    float s = e0 + e1;
    #pragma unroll
    for (int off = 32; off; off >>= 1) s += __shfl_xor(s, off);
    const float inv = 1.0f / s;

    plds[1 + lane] = e0 * inv;
    if (65 + lane < NSl) plds[65 + lane] = e1 * inv;
    if (lane == 0) plds[0] = 0.f;
    __syncthreads();

    // attn output at offset B*NS*H*HD
    float* attn_row = out + BB * NSl * HH * HDl + (((b * HH + h) * NSl) + i) * NSl;
    for (int j = lane; j < NSl; j += 64) attn_row[j] = plds[j];

    // context: lane = channel d
    float c = 0.f;
    for (int j = 1; j < NSl; ++j)
        c += plds[j] * V[(b * NSl + j) * DD + h * HDl + lane];
    out[((b * NSl + i) * HH + h) * HDl + lane] = c;
}

// ---------------------------------------------------------------------------
extern "C" void kernel_launch(void* const* d_in, const int* in_sizes, int n_in,
                              void* d_out, int out_size, void* d_ws, size_t ws_size,
                              hipStream_t stream) {
    const float* desc   = (const float*)d_in[0];
    const float* nve    = (const float*)d_in[1];
    const float* mask_M = (const float*)d_in[2];
    const float* Wq     = (const float*)d_in[3];
    const float* bq     = (const float*)d_in[4];
    const float* Wk     = (const float*)d_in[5];
    const float* bk     = (const float*)d_in[6];
    const float* Wv     = (const float*)d_in[7];
    const float* bv     = (const float*)d_in[8];
    const float* eW1    = (const float*)d_in[9];
    const float* eb1    = (const float*)d_in[10];
    const float* ln_g   = (const float*)d_in[11];
    const float* ln_b   = (const float*)d_in[12];
    const float* eW2    = (const float*)d_in[13];
    const float* eb2    = (const float*)d_in[14];
    const float* aW     = (const float*)d_in[15];
    const float* ab     = (const float*)d_in[16];

    float* ws  = (float*)d_ws;
    float* out = (float*)d_out;

    fold_kernel<<<(3 * HH * DD + 36 + 255) / 256, 256, 0, stream>>>(
        Wq, Wk, eW2, bq, bk, eb2, aW,
        ws + OFF_W2A, ws + OFF_WQA, ws + OFF_WKA, ws + OFF_BF);

    gemm3_kernel<<<dim3(DD / 64, (BB * NSl + 63) / 64, 3), 256, 0, stream>>>(
        desc, nve, eW1, Wv, bv, ws + OFF_P, ws + OFF_Q, ws + OFF_V);

    qk_kernel<<<(BB * NSl * HH * 2 + 255) / 256, 256, 0, stream>>>(
        nve, ws + OFF_WQA, ws + OFF_WKA, ws + OFF_BF, ws + OFF_QA, ws + OFF_KA);

    pair_kernel<<<NPAIR / 4, 256, 0, stream>>>(
        ws + OFF_P, ws + OFF_Q, eb1, ln_g, ln_b, ws + OFF_W2A, ws + OFF_BF, ws + OFF_EL);

    softmax_ctx_kernel<<<BB * HH * NSl, 64, 0, stream>>>(
        ws + OFF_EL, ws + OFF_QA, ws + OFF_KA, mask_M, ab, ws + OFF_V, out);
}

// Round 2
// 159.320 us; speedup vs baseline: 1.8374x; 1.8374x over previous
//
#include <hip/hip_runtime.h>
#include <hip/hip_bf16.h>

#define BB  4
#define SS  127
#define DD  768
#define HH  12
#define HDl 64
#define NSl 128

typedef __attribute__((ext_vector_type(8))) short short8;
typedef __attribute__((ext_vector_type(4))) float f32x4;

// ---- workspace layout (floats) ----
constexpr int OFF_P   = 0;                          // B*S*D
constexpr int OFF_Q   = OFF_P  + BB*SS*DD;          // B*S*D
constexpr int OFF_V   = OFF_Q  + BB*SS*DD;          // B*NS*D
constexpr int OFF_QA  = OFF_V  + BB*NSl*DD;         // B*NS*H
constexpr int OFF_KA  = OFF_QA + BB*NSl*HH;         // B*NS*H
constexpr int OFF_W2T = OFF_KA + BB*NSl*HH;         // D*H (transposed: [c][h])
constexpr int OFF_WQA = OFF_W2T + DD*HH;            // H*D
constexpr int OFF_WKA = OFF_WQA + HH*DD;            // H*D
constexpr int OFF_BF  = OFF_WKA + HH*DD;            // 36: b2a[12], bqa[12], bka[12]
constexpr int OFF_EL  = OFF_BF + 36;                // B*H*NS*NS
constexpr int NPAIR   = BB * NSl * (NSl - 1);

__device__ inline unsigned short f2bf(float f) {
    unsigned int u = __builtin_bit_cast(unsigned int, f);
    u += 0x7fffu + ((u >> 16) & 1u);
    return (unsigned short)(u >> 16);
}

// ---------------------------------------------------------------------------
// Fold kernel: W2T[c][h] = sum_d eW2[c, h*64+d]*ae[d]; WQA[h][c]=Wq[:,h]·aq;
// WKA likewise; 36 bias dots.
// ---------------------------------------------------------------------------
__global__ void fold_kernel(const float* __restrict__ Wq, const float* __restrict__ Wk,
                            const float* __restrict__ eW2,
                            const float* __restrict__ bq, const float* __restrict__ bk,
                            const float* __restrict__ eb2,
                            const float* __restrict__ aW,
                            float* __restrict__ W2T, float* __restrict__ WQA,
                            float* __restrict__ WKA, float* __restrict__ bfold) {
    int idx = blockIdx.x * 256 + threadIdx.x;
    const int total = 3 * HH * DD;
    if (idx < total) {
        int which = idx / (HH * DD);
        int r = idx % (HH * DD);
        int h = r / DD;
        int c = r % DD;
        const float* W = (which == 0) ? eW2 : (which == 1) ? Wq : Wk;
        const float* a = (which == 0) ? (aW + 2 * HDl) : (which == 1) ? aW : (aW + HDl);
        float s = 0.f;
        #pragma unroll 8
        for (int d = 0; d < HDl; ++d) s += W[c * DD + h * HDl + d] * a[d];
        if (which == 0) W2T[c * HH + h] = s;
        else if (which == 1) WQA[h * DD + c] = s;
        else WKA[h * DD + c] = s;
    } else if (idx < total + 36) {
        int r = idx - total;
        int which = r / HH, h = r % HH;
        const float* bb = (which == 0) ? eb2 : (which == 1) ? bq : bk;
        const float* a = (which == 0) ? (aW + 2 * HDl) : (which == 1) ? aW : (aW + HDl);
        float s = 0.f;
        for (int d = 0; d < HDl; ++d) s += bb[h * HDl + d] * a[d];
        bfold[r] = s;
    }
}

// ---------------------------------------------------------------------------
// MFMA bf16 GEMM: z=0: P = desc @ eW1[:D]; z=1: Q = desc @ eW1[D:];
// z=2: V = nve @ Wv + bv.  64x64x(K=64) tiles, 4 waves -> 32x32 each (2x2
// frags of 16x16x32). LDS XOR-swizzled (T2) for conflict-free ds_read_b128.
// ---------------------------------------------------------------------------
__global__ __launch_bounds__(256) void gemm3_mfma(
        const float* __restrict__ desc, const float* __restrict__ nve,
        const float* __restrict__ eW1, const float* __restrict__ Wv,
        const float* __restrict__ bv,
        float* __restrict__ P, float* __restrict__ Qm, float* __restrict__ V) {
    const int z = blockIdx.z;
    const float* A    = (z == 2) ? nve : desc;
    const float* Bm   = (z == 0) ? eW1 : (z == 1) ? (eW1 + DD * DD) : Wv;
    float* C          = (z == 0) ? P : (z == 1) ? Qm : V;
    const int M       = (z == 2) ? (BB * NSl) : (BB * SS);

    __shared__ short As[64 * 64];   // [row][k] bf16, row stride 128B, swizzled
    __shared__ short Bs[64 * 64];   // [col][k] bf16 (B transposed), swizzled

    const int tid  = threadIdx.x;
    const int lane = tid & 63;
    const int w    = tid >> 6;
    const int wr   = w >> 1, wc = w & 1;
    const int brow = blockIdx.y * 64, bcol = blockIdx.x * 64;

    f32x4 acc[2][2] = {};

    for (int k0 = 0; k0 < DD; k0 += 64) {
        // ---- stage A: each thread handles 2 chunks of 8 elements ----
        #pragma unroll
        for (int it = 0; it < 2; ++it) {
            int chunk = tid + it * 256;
            int row = chunk >> 3;          // 8 chunks per row
            int kc  = (chunk & 7) * 8;
            int gm  = brow + row;
            float4 f0 = {0,0,0,0}, f1 = {0,0,0,0};
            if (gm < M) {
                f0 = *(const float4*)(A + gm * DD + k0 + kc);
                f1 = *(const float4*)(A + gm * DD + k0 + kc + 4);
            }
            short8 pk;
            pk[0] = (short)f2bf(f0.x); pk[1] = (short)f2bf(f0.y);
            pk[2] = (short)f2bf(f0.z); pk[3] = (short)f2bf(f0.w);
            pk[4] = (short)f2bf(f1.x); pk[5] = (short)f2bf(f1.y);
            pk[6] = (short)f2bf(f1.z); pk[7] = (short)f2bf(f1.w);
            int byte = (row * 128 + kc * 2) ^ ((row & 7) << 4);
            *(short8*)((char*)As + byte) = pk;
        }
        // ---- stage B transposed: thread t -> col n=t&63, k group g=t>>6 ----
        {
            int n = tid & 63, g = tid >> 6;
            unsigned short ub[16];
            #pragma unroll
            for (int q = 0; q < 16; ++q)
                ub[q] = f2bf(Bm[(k0 + g * 16 + q) * DD + bcol + n]);
            short8 p0, p1;
            #pragma unroll
            for (int q = 0; q < 8; ++q) { p0[q] = (short)ub[q]; p1[q] = (short)ub[q + 8]; }
            int base = n * 128 + g * 32;
            int sw   = (n & 7) << 4;
            *(short8*)((char*)Bs + (base ^ sw))        = p0;
            *(short8*)((char*)Bs + ((base + 16) ^ sw)) = p1;
        }
        __syncthreads();
        // ---- MFMA: 2 k-subtiles of 32 ----
        #pragma unroll
        for (int ks = 0; ks < 2; ++ks) {
            const int kb = ks * 64 + ((lane >> 4) << 4);   // byte offset in row
            short8 af[2], bfr[2];
            #pragma unroll
            for (int mi = 0; mi < 2; ++mi) {
                int row = wr * 32 + mi * 16 + (lane & 15);
                af[mi] = *(const short8*)((char*)As + ((row * 128 + kb) ^ ((row & 7) << 4)));
            }
            #pragma unroll
            for (int ni = 0; ni < 2; ++ni) {
                int col = wc * 32 + ni * 16 + (lane & 15);
                bfr[ni] = *(const short8*)((char*)Bs + ((col * 128 + kb) ^ ((col & 7) << 4)));
            }
            #pragma unroll
            for (int mi = 0; mi < 2; ++mi)
                #pragma unroll
                for (int ni = 0; ni < 2; ++ni)
                    acc[mi][ni] = __builtin_amdgcn_mfma_f32_16x16x32_bf16(
                        af[mi], bfr[ni], acc[mi][ni], 0, 0, 0);
        }
        __syncthreads();
    }
    // ---- epilogue: C/D map col=lane&15, row=(lane>>4)*4+r ----
    #pragma unroll
    for (int mi = 0; mi < 2; ++mi)
        #pragma unroll
        for (int ni = 0; ni < 2; ++ni) {
            int gcol = bcol + wc * 32 + ni * 16 + (lane & 15);
            float badd = (z == 2) ? bv[gcol] : 0.f;
            #pragma unroll
            for (int r = 0; r < 4; ++r) {
                int grow = brow + wr * 32 + mi * 16 + ((lane >> 4) << 2) + r;
                if (grow < M) C[grow * DD + gcol] = acc[mi][ni][r] + badd;
            }
        }
}

// ---------------------------------------------------------------------------
// qa/ka: one wave per output. 12288 outputs.
// ---------------------------------------------------------------------------
__global__ void qk_kernel(const float* __restrict__ nve,
                          const float* __restrict__ WQA, const float* __restrict__ WKA,
                          const float* __restrict__ bfold,
                          float* __restrict__ qa, float* __restrict__ ka) {
    int wid = blockIdx.x * 4 + (threadIdx.x >> 6);
    int lane = threadIdx.x & 63;
    if (wid >= BB * NSl * HH * 2) return;
    int which = wid & 1;
    int r = wid >> 1;
    int h = r % HH;
    int t = (r / HH) % NSl;
    int b = r / (HH * NSl);
    const float* W = (which ? WKA : WQA) + h * DD;
    const float* row = nve + (b * NSl + t) * DD;
    float s = 0.f;
    #pragma unroll
    for (int rr = 0; rr < 12; ++rr) {
        int c = lane + 64 * rr;
        s += row[c] * W[c];
    }
    #pragma unroll
    for (int off = 32; off; off >>= 1) s += __shfl_xor(s, off);
    if (lane == 0)
        (which ? ka : qa)[(b * NSl + t) * HH + h] = s + bfold[12 + which * 12 + h];
}

// ---------------------------------------------------------------------------
// Pair kernel: one wave per (b, i, j>=1).
//   x = P[pi] + Q[j-1] + eb1; y = relu(LN(x)); e_log[b,h,i,j] = y·W2T[:,h]+b2a
// ---------------------------------------------------------------------------
__global__ void pair_kernel(const float* __restrict__ P, const float* __restrict__ Qm,
                            const float* __restrict__ eb1,
                            const float* __restrict__ ln_g, const float* __restrict__ ln_b,
                            const float* __restrict__ W2T, const float* __restrict__ bfold,
                            float* __restrict__ e_log) {
    int wid = (blockIdx.x * blockDim.x + threadIdx.x) >> 6;
    int lane = threadIdx.x & 63;
    if (wid >= NPAIR) return;
    int b = wid / (NSl * (NSl - 1));
    int rem = wid % (NSl * (NSl - 1));
    int i = rem / (NSl - 1);
    int j = 1 + rem % (NSl - 1);
    int pi = (i == 0) ? (j - 1) : (i - 1);

    const float* prow = P + (b * SS + pi) * DD;
    const float* qrow = Qm + (b * SS + (j - 1)) * DD;

    float x[12];
    float sum = 0.f, sumsq = 0.f;
    #pragma unroll
    for (int r = 0; r < 12; ++r) {
        int c = lane + 64 * r;
        float xv = prow[c] + qrow[c] + eb1[c];
        x[r] = xv;
        sum += xv;
        sumsq += xv * xv;
    }
    #pragma unroll
    for (int off = 32; off; off >>= 1) {
        sum += __shfl_xor(sum, off);
        sumsq += __shfl_xor(sumsq, off);
    }
    const float mean = sum * (1.f / DD);
    const float var = sumsq * (1.f / DD) - mean * mean;
    const float sc = rsqrtf(var + 1e-5f);

    float acc[12] = {};
    #pragma unroll
    for (int r = 0; r < 12; ++r) {
        int c = lane + 64 * r;
        float y = (x[r] - mean) * sc * ln_g[c] + ln_b[c];
        y = fmaxf(y, 0.f);
        const float4* wp = (const float4*)(W2T + c * HH);
        float4 w0 = wp[0], w1 = wp[1], w2 = wp[2];
        acc[0] += y * w0.x; acc[1]  += y * w0.y; acc[2]  += y * w0.z; acc[3]  += y * w0.w;
        acc[4] += y * w1.x; acc[5]  += y * w1.y; acc[6]  += y * w1.z; acc[7]  += y * w1.w;
        acc[8] += y * w2.x; acc[9]  += y * w2.y; acc[10] += y * w2.z; acc[11] += y * w2.w;
    }
    #pragma unroll
    for (int h = 0; h < 12; ++h) {
        #pragma unroll
        for (int off = 32; off; off >>= 1) acc[h] += __shfl_xor(acc[h], off);
    }
    float outv = acc[0];
    #pragma unroll
    for (int h = 1; h < 12; ++h)
        if (lane == h) outv = acc[h];
    if (lane < HH)
        e_log[(((b * HH + lane) * NSl) + i) * NSl + j] = outv + bfold[lane];
}

// ---------------------------------------------------------------------------
// Softmax + context: one wave per (b,h,i). e_log now [b,h,i,j] (coalesced).
// ---------------------------------------------------------------------------
__global__ void softmax_ctx_kernel(const float* __restrict__ e_log,
                                   const float* __restrict__ qa, const float* __restrict__ ka,
                                   const float* __restrict__ mask_M, const float* __restrict__ ab,
                                   const float* __restrict__ V,
                                   float* __restrict__ out) {
    const int wid = blockIdx.x;
    const int lane = threadIdx.x;
    const int b = wid / (HH * NSl);
    const int rem = wid % (HH * NSl);
    const int h = rem / NSl;
    const int i = rem % NSl;

    __shared__ float plds[NSl];

    const float abv = ab[0];
    const float qv = qa[(b * NSl + i) * HH + h];
    const float* e_row = e_log + (((b * HH + h) * NSl) + i) * NSl;

    float lg[2];
    bool valid[2];
    #pragma unroll
    for (int s = 0; s < 2; ++s) {
        int j = 1 + lane + 64 * s;
        bool v = (j < NSl) && !(i >= 1 && j == i);
        float l = -1e30f;
        if (v) {
            l = e_row[j] + qv + ka[(b * NSl + j) * HH + h] + abv;
            if (i >= 1) {
                float p = mask_M[((b * HH + h) * SS + (i - 1)) * SS + (j - 1)];
                p = fminf(fmaxf(p, 1e-6f), 1.0f - 1e-6f);
                l += logf(p) - logf(1.0f - p);
            }
        }
        lg[s] = l;
        valid[s] = v;
    }
    float m = fmaxf(lg[0], lg[1]);
    #pragma unroll
    for (int off = 32; off; off >>= 1) m = fmaxf(m, __shfl_xor(m, off));
    float e0 = valid[0] ? expf(lg[0] - m) : 0.f;
    float e1 = valid[1] ? expf(lg[1] - m) : 0.f;
    float s = e0 + e1;
    #pragma unroll
    for (int off = 32; off; off >>= 1) s += __shfl_xor(s, off);
    const float inv = 1.0f / s;

    plds[1 + lane] = e0 * inv;
    if (65 + lane < NSl) plds[65 + lane] = e1 * inv;
    if (lane == 0) plds[0] = 0.f;
    __syncthreads();

    float* attn_row = out + BB * NSl * HH * HDl + (((b * HH + h) * NSl) + i) * NSl;
    for (int j = lane; j < NSl; j += 64) attn_row[j] = plds[j];

    // context: lane = channel d; 4-way unrolled j loop (plds[0]==0)
    const float* vb = V + b * NSl * DD + h * HDl + lane;
    float c0 = 0.f, c1 = 0.f, c2 = 0.f, c3 = 0.f;
    for (int j = 0; j < NSl; j += 4) {
        c0 += plds[j]     * vb[(j)     * DD];
        c1 += plds[j + 1] * vb[(j + 1) * DD];
        c2 += plds[j + 2] * vb[(j + 2) * DD];
        c3 += plds[j + 3] * vb[(j + 3) * DD];
    }
    out[((b * NSl + i) * HH + h) * HDl + lane] = (c0 + c1) + (c2 + c3);
}

// ---------------------------------------------------------------------------
extern "C" void kernel_launch(void* const* d_in, const int* in_sizes, int n_in,
                              void* d_out, int out_size, void* d_ws, size_t ws_size,
                              hipStream_t stream) {
    const float* desc   = (const float*)d_in[0];
    const float* nve    = (const float*)d_in[1];
    const float* mask_M = (const float*)d_in[2];
    const float* Wq     = (const float*)d_in[3];
    const float* bq     = (const float*)d_in[4];
    const float* Wk     = (const float*)d_in[5];
    const float* bk     = (const float*)d_in[6];
    const float* Wv     = (const float*)d_in[7];
    const float* bv     = (const float*)d_in[8];
    const float* eW1    = (const float*)d_in[9];
    const float* eb1    = (const float*)d_in[10];
    const float* ln_g   = (const float*)d_in[11];
    const float* ln_b   = (const float*)d_in[12];
    const float* eW2    = (const float*)d_in[13];
    const float* eb2    = (const float*)d_in[14];
    const float* aW     = (const float*)d_in[15];
    const float* ab     = (const float*)d_in[16];

    float* ws  = (float*)d_ws;
    float* out = (float*)d_out;

    fold_kernel<<<(3 * HH * DD + 36 + 255) / 256, 256, 0, stream>>>(
        Wq, Wk, eW2, bq, bk, eb2, aW,
        ws + OFF_W2T, ws + OFF_WQA, ws + OFF_WKA, ws + OFF_BF);

    gemm3_mfma<<<dim3(DD / 64, (BB * NSl + 63) / 64, 3), 256, 0, stream>>>(
        desc, nve, eW1, Wv, bv, ws + OFF_P, ws + OFF_Q, ws + OFF_V);

    qk_kernel<<<(BB * NSl * HH * 2 + 3) / 4, 256, 0, stream>>>(
        nve, ws + OFF_WQA, ws + OFF_WKA, ws + OFF_BF, ws + OFF_QA, ws + OFF_KA);

    pair_kernel<<<NPAIR / 4, 256, 0, stream>>>(
        ws + OFF_P, ws + OFF_Q, eb1, ln_g, ln_b, ws + OFF_W2T, ws + OFF_BF, ws + OFF_EL);

    softmax_ctx_kernel<<<BB * HH * NSl, 64, 0, stream>>>(
        ws + OFF_EL, ws + OFF_QA, ws + OFF_KA, mask_M, ab, ws + OFF_V, out);
}

// Round 3
// 116.049 us; speedup vs baseline: 2.5224x; 1.3729x over previous
//
#include <hip/hip_runtime.h>
#include <hip/hip_bf16.h>

#define BB  4
#define SS  127
#define DD  768
#define HH  12
#define HDl 64
#define NSl 128

typedef __attribute__((ext_vector_type(8))) short short8;
typedef __attribute__((ext_vector_type(4))) float f32x4;

// ---- workspace layout (floats) ----
constexpr int OFF_P   = 0;                          // B*S*D
constexpr int OFF_Q   = OFF_P  + BB*SS*DD;          // B*S*D (Q' = desc@eW1[D:] + eb1)
constexpr int OFF_V   = OFF_Q  + BB*SS*DD;          // B*NS*D
constexpr int OFF_QA  = OFF_V  + BB*NSl*DD;         // B*NS*H
constexpr int OFF_KA  = OFF_QA + BB*NSl*HH;         // B*NS*H
constexpr int OFF_W2B = OFF_KA + BB*NSl*HH;         // 16*768 bf16 = 6144 floats
constexpr int OFF_WQA = OFF_W2B + 6144;             // H*D
constexpr int OFF_WKA = OFF_WQA + HH*DD;            // H*D
constexpr int OFF_BF  = OFF_WKA + HH*DD;            // 36
constexpr int OFF_SP  = OFF_BF + 64;                // B*128
constexpr int OFF_SSP = OFF_SP + BB*128;
constexpr int OFF_SQ  = OFF_SSP + BB*128;
constexpr int OFF_SSQ = OFF_SQ + BB*128;
constexpr int OFF_G   = OFF_SSQ + BB*128;           // B*128*128
constexpr int OFF_EL  = OFF_G + BB*128*128;         // B*H*NS*NS

__device__ inline unsigned short f2bf(float f) {
    unsigned int u = __builtin_bit_cast(unsigned int, f);
    u += 0x7fffu + ((u >> 16) & 1u);
    return (unsigned short)(u >> 16);
}

// ---------------------------------------------------------------------------
// Fold: W2B[h][c] (bf16, h padded to 16) = eW2[c, h*64+d]·ae; WQA/WKA; biases.
// ---------------------------------------------------------------------------
__global__ void fold_kernel(const float* __restrict__ Wq, const float* __restrict__ Wk,
                            const float* __restrict__ eW2,
                            const float* __restrict__ bq, const float* __restrict__ bk,
                            const float* __restrict__ eb2,
                            const float* __restrict__ aW,
                            unsigned short* __restrict__ W2Bu, float* __restrict__ WQA,
                            float* __restrict__ WKA, float* __restrict__ bfold) {
    int idx = blockIdx.x * 256 + threadIdx.x;
    const int total = 3 * HH * DD;
    if (idx < total) {
        int which = idx / (HH * DD);
        int r = idx % (HH * DD);
        int h = r / DD;
        int c = r % DD;
        const float* W = (which == 0) ? eW2 : (which == 1) ? Wq : Wk;
        const float* a = (which == 0) ? (aW + 2 * HDl) : (which == 1) ? aW : (aW + HDl);
        float s = 0.f;
        #pragma unroll 8
        for (int d = 0; d < HDl; ++d) s += W[c * DD + h * HDl + d] * a[d];
        if (which == 0) W2Bu[h * DD + c] = f2bf(s);
        else if (which == 1) WQA[h * DD + c] = s;
        else WKA[h * DD + c] = s;
    } else if (idx < total + 36) {
        int r = idx - total;
        int which = r / HH, h = r % HH;
        const float* bb = (which == 0) ? eb2 : (which == 1) ? bq : bk;
        const float* a = (which == 0) ? (aW + 2 * HDl) : (which == 1) ? aW : (aW + HDl);
        float s = 0.f;
        for (int d = 0; d < HDl; ++d) s += bb[h * HDl + d] * a[d];
        bfold[r] = s;
    } else if (idx < total + 36 + 4 * DD) {
        W2Bu[12 * DD + (idx - total - 36)] = 0;   // pad heads 12..15
    }
}

// ---------------------------------------------------------------------------
// MFMA bf16 GEMM: z=0: P=desc@eW1[:D]; z=1: Q'=desc@eW1[D:]+eb1; z=2: V=nve@Wv+bv
// ---------------------------------------------------------------------------
__global__ __launch_bounds__(256) void gemm3_mfma(
        const float* __restrict__ desc, const float* __restrict__ nve,
        const float* __restrict__ eW1, const float* __restrict__ Wv,
        const float* __restrict__ bv, const float* __restrict__ eb1,
        float* __restrict__ P, float* __restrict__ Qm, float* __restrict__ V) {
    const int z = blockIdx.z;
    const float* A    = (z == 2) ? nve : desc;
    const float* Bm   = (z == 0) ? eW1 : (z == 1) ? (eW1 + DD * DD) : Wv;
    const float* bias = (z == 0) ? nullptr : (z == 1) ? eb1 : bv;
    float* C          = (z == 0) ? P : (z == 1) ? Qm : V;
    const int M       = (z == 2) ? (BB * NSl) : (BB * SS);

    __shared__ short As[64 * 64];
    __shared__ short Bs[64 * 64];

    const int tid  = threadIdx.x;
    const int lane = tid & 63;
    const int w    = tid >> 6;
    const int wr   = w >> 1, wc = w & 1;
    const int brow = blockIdx.y * 64, bcol = blockIdx.x * 64;

    f32x4 acc[2][2] = {};

    for (int k0 = 0; k0 < DD; k0 += 64) {
        #pragma unroll
        for (int it = 0; it < 2; ++it) {
            int chunk = tid + it * 256;
            int row = chunk >> 3;
            int kc  = (chunk & 7) * 8;
            int gm  = brow + row;
            float4 f0 = {0,0,0,0}, f1 = {0,0,0,0};
            if (gm < M) {
                f0 = *(const float4*)(A + gm * DD + k0 + kc);
                f1 = *(const float4*)(A + gm * DD + k0 + kc + 4);
            }
            short8 pk;
            pk[0] = (short)f2bf(f0.x); pk[1] = (short)f2bf(f0.y);
            pk[2] = (short)f2bf(f0.z); pk[3] = (short)f2bf(f0.w);
            pk[4] = (short)f2bf(f1.x); pk[5] = (short)f2bf(f1.y);
            pk[6] = (short)f2bf(f1.z); pk[7] = (short)f2bf(f1.w);
            int byte = (row * 128 + kc * 2) ^ ((row & 7) << 4);
            *(short8*)((char*)As + byte) = pk;
        }
        {
            int n = tid & 63, g = tid >> 6;
            unsigned short ub[16];
            #pragma unroll
            for (int q = 0; q < 16; ++q)
                ub[q] = f2bf(Bm[(k0 + g * 16 + q) * DD + bcol + n]);
            short8 p0, p1;
            #pragma unroll
            for (int q = 0; q < 8; ++q) { p0[q] = (short)ub[q]; p1[q] = (short)ub[q + 8]; }
            int base = n * 128 + g * 32;
            int sw   = (n & 7) << 4;
            *(short8*)((char*)Bs + (base ^ sw))        = p0;
            *(short8*)((char*)Bs + ((base + 16) ^ sw)) = p1;
        }
        __syncthreads();
        #pragma unroll
        for (int ks = 0; ks < 2; ++ks) {
            const int kb = ks * 64 + ((lane >> 4) << 4);
            short8 af[2], bfr[2];
            #pragma unroll
            for (int mi = 0; mi < 2; ++mi) {
                int row = wr * 32 + mi * 16 + (lane & 15);
                af[mi] = *(const short8*)((char*)As + ((row * 128 + kb) ^ ((row & 7) << 4)));
            }
            #pragma unroll
            for (int ni = 0; ni < 2; ++ni) {
                int col = wc * 32 + ni * 16 + (lane & 15);
                bfr[ni] = *(const short8*)((char*)Bs + ((col * 128 + kb) ^ ((col & 7) << 4)));
            }
            #pragma unroll
            for (int mi = 0; mi < 2; ++mi)
                #pragma unroll
                for (int ni = 0; ni < 2; ++ni)
                    acc[mi][ni] = __builtin_amdgcn_mfma_f32_16x16x32_bf16(
                        af[mi], bfr[ni], acc[mi][ni], 0, 0, 0);
        }
        __syncthreads();
    }
    #pragma unroll
    for (int mi = 0; mi < 2; ++mi)
        #pragma unroll
        for (int ni = 0; ni < 2; ++ni) {
            int gcol = bcol + wc * 32 + ni * 16 + (lane & 15);
            float badd = bias ? bias[gcol] : 0.f;
            #pragma unroll
            for (int r = 0; r < 4; ++r) {
                int grow = brow + wr * 32 + mi * 16 + ((lane >> 4) << 2) + r;
                if (grow < M) C[grow * DD + gcol] = acc[mi][ni][r] + badd;
            }
        }
}

// ---------------------------------------------------------------------------
// Gram: G[b,pi,qj] = P[b,pi,:]·Q'[b,qj,:]  (127x127, K=768, bf16 MFMA)
// ---------------------------------------------------------------------------
__global__ __launch_bounds__(256) void gram_kernel(
        const float* __restrict__ Pp, const float* __restrict__ Qp,
        float* __restrict__ G) {
    const int b = blockIdx.z;
    __shared__ short As[64 * 64];
    __shared__ short Bs[64 * 64];

    const int tid  = threadIdx.x;
    const int lane = tid & 63;
    const int w    = tid >> 6;
    const int wr   = w >> 1, wc = w & 1;
    const int brow = blockIdx.y * 64, bcol = blockIdx.x * 64;
    const float* Pb = Pp + b * SS * DD;
    const float* Qb = Qp + b * SS * DD;

    f32x4 acc[2][2] = {};

    for (int k0 = 0; k0 < DD; k0 += 64) {
        #pragma unroll
        for (int it = 0; it < 4; ++it) {
            int chunk = tid + (it & 1) * 256;
            int row = chunk >> 3;
            int kc  = (chunk & 7) * 8;
            const float* src = (it < 2) ? Pb : Qb;
            int base = (it < 2) ? brow : bcol;
            short* dst = (it < 2) ? As : Bs;
            int gm = base + row;
            float4 f0 = {0,0,0,0}, f1 = {0,0,0,0};
            if (gm < SS) {
                f0 = *(const float4*)(src + gm * DD + k0 + kc);
                f1 = *(const float4*)(src + gm * DD + k0 + kc + 4);
            }
            short8 pk;
            pk[0] = (short)f2bf(f0.x); pk[1] = (short)f2bf(f0.y);
            pk[2] = (short)f2bf(f0.z); pk[3] = (short)f2bf(f0.w);
            pk[4] = (short)f2bf(f1.x); pk[5] = (short)f2bf(f1.y);
            pk[6] = (short)f2bf(f1.z); pk[7] = (short)f2bf(f1.w);
            int byte = (row * 128 + kc * 2) ^ ((row & 7) << 4);
            *(short8*)((char*)dst + byte) = pk;
        }
        __syncthreads();
        #pragma unroll
        for (int ks = 0; ks < 2; ++ks) {
            const int kb = ks * 64 + ((lane >> 4) << 4);
            short8 af[2], bfr[2];
            #pragma unroll
            for (int mi = 0; mi < 2; ++mi) {
                int row = wr * 32 + mi * 16 + (lane & 15);
                af[mi] = *(const short8*)((char*)As + ((row * 128 + kb) ^ ((row & 7) << 4)));
            }
            #pragma unroll
            for (int ni = 0; ni < 2; ++ni) {
                int col = wc * 32 + ni * 16 + (lane & 15);
                bfr[ni] = *(const short8*)((char*)Bs + ((col * 128 + kb) ^ ((col & 7) << 4)));
            }
            #pragma unroll
            for (int mi = 0; mi < 2; ++mi)
                #pragma unroll
                for (int ni = 0; ni < 2; ++ni)
                    acc[mi][ni] = __builtin_amdgcn_mfma_f32_16x16x32_bf16(
                        af[mi], bfr[ni], acc[mi][ni], 0, 0, 0);
        }
        __syncthreads();
    }
    #pragma unroll
    for (int mi = 0; mi < 2; ++mi)
        #pragma unroll
        for (int ni = 0; ni < 2; ++ni) {
            int gcol = bcol + wc * 32 + ni * 16 + (lane & 15);
            #pragma unroll
            for (int r = 0; r < 4; ++r) {
                int grow = brow + wr * 32 + mi * 16 + ((lane >> 4) << 2) + r;
                G[b * 128 * 128 + grow * 128 + gcol] = acc[mi][ni][r];
            }
        }
}

// ---------------------------------------------------------------------------
// Row stats: SP/SSP over P rows, SQ/SSQ over Q' rows. One wave per (b,row,which).
// ---------------------------------------------------------------------------
__global__ void rowstat_kernel(const float* __restrict__ Pp, const float* __restrict__ Qp,
                               float* __restrict__ SP, float* __restrict__ SSP,
                               float* __restrict__ SQ, float* __restrict__ SSQ) {
    int wid = blockIdx.x * 4 + (threadIdx.x >> 6);
    int lane = threadIdx.x & 63;
    if (wid >= BB * SS * 2) return;
    int which = wid & 1;
    int row = (wid >> 1) % SS;
    int b = (wid >> 1) / SS;
    const float* src = (which ? Qp : Pp) + (b * SS + row) * DD;
    float s = 0.f, ss = 0.f;
    #pragma unroll
    for (int r = 0; r < 12; ++r) {
        float v = src[lane + 64 * r];
        s += v;
        ss += v * v;
    }
    #pragma unroll
    for (int off = 32; off; off >>= 1) {
        s += __shfl_xor(s, off);
        ss += __shfl_xor(ss, off);
    }
    if (lane == 0) {
        (which ? SQ : SP)[b * 128 + row] = s;
        (which ? SSQ : SSP)[b * 128 + row] = ss;
    }
}

// ---------------------------------------------------------------------------
// qa/ka: one wave per output.
// ---------------------------------------------------------------------------
__global__ void qk_kernel(const float* __restrict__ nve,
                          const float* __restrict__ WQA, const float* __restrict__ WKA,
                          const float* __restrict__ bfold,
                          float* __restrict__ qa, float* __restrict__ ka) {
    int wid = blockIdx.x * 4 + (threadIdx.x >> 6);
    int lane = threadIdx.x & 63;
    if (wid >= BB * NSl * HH * 2) return;
    int which = wid & 1;
    int r = wid >> 1;
    int h = r % HH;
    int t = (r / HH) % NSl;
    int b = r / (HH * NSl);
    const float* W = (which ? WKA : WQA) + h * DD;
    const float* row = nve + (b * NSl + t) * DD;
    float s = 0.f;
    #pragma unroll
    for (int rr = 0; rr < 12; ++rr) {
        int c = lane + 64 * rr;
        s += row[c] * W[c];
    }
    #pragma unroll
    for (int off = 32; off; off >>= 1) s += __shfl_xor(s, off);
    if (lane == 0)
        (which ? ka : qa)[(b * NSl + t) * HH + h] = s + bfold[12 + which * 12 + h];
}

// ---------------------------------------------------------------------------
// Pair MFMA: block = (b, 8x8 pi/qj tile), 4 waves, wave = 4x4 pairs.
// Lane l: pair = l&15 (dpi=(l&15)>>2, dqj=(l&15)&3), kgroup = l>>4.
// y = relu(LN(P_pi + Q'_qj)) packed bf16 = A-frag; W2B LDS = B-frag;
// acc[16 pairs x 16 h] via 24 MFMAs. Scatter: diag->(0,qj+1), else (pi+1,qj+1).
// ---------------------------------------------------------------------------
__global__ __launch_bounds__(256) void pair_mfma(
        const float* __restrict__ Pp, const float* __restrict__ Qp,
        const float* __restrict__ ln_g, const float* __restrict__ ln_b,
        const unsigned short* __restrict__ W2Bu,
        const float* __restrict__ SP, const float* __restrict__ SSP,
        const float* __restrict__ SQ, const float* __restrict__ SSQ,
        const float* __restrict__ G, const float* __restrict__ bfold,
        float* __restrict__ e_log) {
    __shared__ char w2l[16 * 768 * 2];
    const int tid = threadIdx.x;
    #pragma unroll
    for (int it = 0; it < 6; ++it) {
        int m = tid + it * 256;              // short8 chunk id, 1536 total
        int col = m / 96, rem = m % 96;
        int byte = (col * 1536 + rem * 16) ^ ((col & 7) << 4);
        *(short8*)(w2l + byte) = ((const short8*)W2Bu)[m];
    }
    __syncthreads();

    const int b = blockIdx.z;
    const int lane = tid & 63;
    const int w = tid >> 6;
    const int pi0 = blockIdx.y * 8 + (w >> 1) * 4;
    const int qj0 = blockIdx.x * 8 + (w & 1) * 4;
    const int pr = lane & 15;
    const int dpi = pr >> 2, dqj = pr & 3;
    const int pi = pi0 + dpi, qj = qj0 + dqj;
    const int pic = min(pi, SS - 1), qjc = min(qj, SS - 1);
    const int kg = lane >> 4;

    const float mean = (SP[b * 128 + pic] + SQ[b * 128 + qjc]) * (1.f / DD);
    const float sumsq = SSP[b * 128 + pic] + 2.f * G[b * 128 * 128 + pic * 128 + qjc]
                      + SSQ[b * 128 + qjc];
    const float var = sumsq * (1.f / DD) - mean * mean;
    const float sc = rsqrtf(var + 1e-5f);

    const float* prow = Pp + (b * SS + pic) * DD;
    const float* qrow = Qp + (b * SS + qjc) * DD;
    const int hc = lane & 15;
    const int bbase = hc * 1536;
    const int bxor = (hc & 7) << 4;

    f32x4 acc = {};
    #pragma unroll 4
    for (int ks = 0; ks < 24; ++ks) {
        const int c0 = ks * 32 + kg * 8;
        float4 p0 = *(const float4*)(prow + c0);
        float4 p1 = *(const float4*)(prow + c0 + 4);
        float4 q0 = *(const float4*)(qrow + c0);
        float4 q1 = *(const float4*)(qrow + c0 + 4);
        float4 g0 = *(const float4*)(ln_g + c0);
        float4 g1 = *(const float4*)(ln_g + c0 + 4);
        float4 b0 = *(const float4*)(ln_b + c0);
        float4 b1 = *(const float4*)(ln_b + c0 + 4);
        float y[8];
        y[0] = fmaxf((p0.x + q0.x - mean) * sc * g0.x + b0.x, 0.f);
        y[1] = fmaxf((p0.y + q0.y - mean) * sc * g0.y + b0.y, 0.f);
        y[2] = fmaxf((p0.z + q0.z - mean) * sc * g0.z + b0.z, 0.f);
        y[3] = fmaxf((p0.w + q0.w - mean) * sc * g0.w + b0.w, 0.f);
        y[4] = fmaxf((p1.x + q1.x - mean) * sc * g1.x + b1.x, 0.f);
        y[5] = fmaxf((p1.y + q1.y - mean) * sc * g1.y + b1.y, 0.f);
        y[6] = fmaxf((p1.z + q1.z - mean) * sc * g1.z + b1.z, 0.f);
        y[7] = fmaxf((p1.w + q1.w - mean) * sc * g1.w + b1.w, 0.f);
        short8 af;
        #pragma unroll
        for (int q = 0; q < 8; ++q) af[q] = (short)f2bf(y[q]);
        short8 bf = *(const short8*)(w2l + ((bbase + ks * 64 + kg * 16) ^ bxor));
        acc = __builtin_amdgcn_mfma_f32_16x16x32_bf16(af, bf, acc, 0, 0, 0);
    }

    // epilogue: lane holds h = lane&15, pairs p = (lane>>4)*4 + r
    const int h = lane & 15;
    if (h < HH) {
        const float badd = bfold[h];
        #pragma unroll
        for (int r = 0; r < 4; ++r) {
            int p = (lane >> 4) * 4 + r;
            int ppi = pi0 + (p >> 2), pqj = qj0 + (p & 3);
            if (ppi < SS && pqj < SS) {
                int i = (ppi == pqj) ? 0 : (ppi + 1);
                int j = pqj + 1;
                e_log[(((b * HH + h) * NSl) + i) * NSl + j] = acc[r] + badd;
            }
        }
    }
}

// ---------------------------------------------------------------------------
// Softmax + context: one wave per (b,h,i).
// ---------------------------------------------------------------------------
__global__ void softmax_ctx_kernel(const float* __restrict__ e_log,
                                   const float* __restrict__ qa, const float* __restrict__ ka,
                                   const float* __restrict__ mask_M, const float* __restrict__ ab,
                                   const float* __restrict__ V,
                                   float* __restrict__ out) {
    const int wid = blockIdx.x;
    const int lane = threadIdx.x;
    const int b = wid / (HH * NSl);
    const int rem = wid % (HH * NSl);
    const int h = rem / NSl;
    const int i = rem % NSl;

    __shared__ float plds[NSl];

    const float abv = ab[0];
    const float qv = qa[(b * NSl + i) * HH + h];
    const float* e_row = e_log + (((b * HH + h) * NSl) + i) * NSl;

    float lg[2];
    bool valid[2];
    #pragma unroll
    for (int s = 0; s < 2; ++s) {
        int j = 1 + lane + 64 * s;
        bool v = (j < NSl) && !(i >= 1 && j == i);
        float l = -1e30f;
        if (v) {
            l = e_row[j] + qv + ka[(b * NSl + j) * HH + h] + abv;
            if (i >= 1) {
                float p = mask_M[((b * HH + h) * SS + (i - 1)) * SS + (j - 1)];
                p = fminf(fmaxf(p, 1e-6f), 1.0f - 1e-6f);
                l += logf(p) - logf(1.0f - p);
            }
        }
        lg[s] = l;
        valid[s] = v;
    }
    float m = fmaxf(lg[0], lg[1]);
    #pragma unroll
    for (int off = 32; off; off >>= 1) m = fmaxf(m, __shfl_xor(m, off));
    float e0 = valid[0] ? expf(lg[0] - m) : 0.f;
    float e1 = valid[1] ? expf(lg[1] - m) : 0.f;
    float s = e0 + e1;
    #pragma unroll
    for (int off = 32; off; off >>= 1) s += __shfl_xor(s, off);
    const float inv = 1.0f / s;

    plds[1 + lane] = e0 * inv;
    if (65 + lane < NSl) plds[65 + lane] = e1 * inv;
    if (lane == 0) plds[0] = 0.f;
    __syncthreads();

    float* attn_row = out + BB * NSl * HH * HDl + (((b * HH + h) * NSl) + i) * NSl;
    for (int j = lane; j < NSl; j += 64) attn_row[j] = plds[j];

    const float* vb = V + b * NSl * DD + h * HDl + lane;
    float c0 = 0.f, c1 = 0.f, c2 = 0.f, c3 = 0.f;
    for (int j = 0; j < NSl; j += 4) {
        c0 += plds[j]     * vb[(j)     * DD];
        c1 += plds[j + 1] * vb[(j + 1) * DD];
        c2 += plds[j + 2] * vb[(j + 2) * DD];
        c3 += plds[j + 3] * vb[(j + 3) * DD];
    }
    out[((b * NSl + i) * HH + h) * HDl + lane] = (c0 + c1) + (c2 + c3);
}

// ---------------------------------------------------------------------------
extern "C" void kernel_launch(void* const* d_in, const int* in_sizes, int n_in,
                              void* d_out, int out_size, void* d_ws, size_t ws_size,
                              hipStream_t stream) {
    const float* desc   = (const float*)d_in[0];
    const float* nve    = (const float*)d_in[1];
    const float* mask_M = (const float*)d_in[2];
    const float* Wq     = (const float*)d_in[3];
    const float* bq     = (const float*)d_in[4];
    const float* Wk     = (const float*)d_in[5];
    const float* bk     = (const float*)d_in[6];
    const float* Wv     = (const float*)d_in[7];
    const float* bv     = (const float*)d_in[8];
    const float* eW1    = (const float*)d_in[9];
    const float* eb1    = (const float*)d_in[10];
    const float* ln_g   = (const float*)d_in[11];
    const float* ln_b   = (const float*)d_in[12];
    const float* eW2    = (const float*)d_in[13];
    const float* eb2    = (const float*)d_in[14];
    const float* aW     = (const float*)d_in[15];
    const float* ab     = (const float*)d_in[16];

    float* ws  = (float*)d_ws;
    float* out = (float*)d_out;
    unsigned short* W2Bu = (unsigned short*)(ws + OFF_W2B);

    fold_kernel<<<(3 * HH * DD + 36 + 4 * DD + 255) / 256, 256, 0, stream>>>(
        Wq, Wk, eW2, bq, bk, eb2, aW,
        W2Bu, ws + OFF_WQA, ws + OFF_WKA, ws + OFF_BF);

    gemm3_mfma<<<dim3(DD / 64, (BB * NSl + 63) / 64, 3), 256, 0, stream>>>(
        desc, nve, eW1, Wv, bv, eb1, ws + OFF_P, ws + OFF_Q, ws + OFF_V);

    gram_kernel<<<dim3(2, 2, BB), 256, 0, stream>>>(
        ws + OFF_P, ws + OFF_Q, ws + OFF_G);

    rowstat_kernel<<<(BB * SS * 2 + 3) / 4, 256, 0, stream>>>(
        ws + OFF_P, ws + OFF_Q,
        ws + OFF_SP, ws + OFF_SSP, ws + OFF_SQ, ws + OFF_SSQ);

    qk_kernel<<<(BB * NSl * HH * 2 + 3) / 4, 256, 0, stream>>>(
        nve, ws + OFF_WQA, ws + OFF_WKA, ws + OFF_BF, ws + OFF_QA, ws + OFF_KA);

    pair_mfma<<<dim3(16, 16, BB), 256, 0, stream>>>(
        ws + OFF_P, ws + OFF_Q, ln_g, ln_b, W2Bu,
        ws + OFF_SP, ws + OFF_SSP, ws + OFF_SQ, ws + OFF_SSQ,
        ws + OFF_G, ws + OFF_BF, ws + OFF_EL);

    softmax_ctx_kernel<<<BB * HH * NSl, 64, 0, stream>>>(
        ws + OFF_EL, ws + OFF_QA, ws + OFF_KA, mask_M, ab, ws + OFF_V, out);
}

// Round 5
// 68.188 us; speedup vs baseline: 4.2929x; 1.7019x over previous
//
#include <hip/hip_runtime.h>
#include <hip/hip_bf16.h>

#define BB  4
#define SS  127
#define DD  768
#define HH  12
#define HDl 64
#define NSl 128

typedef __attribute__((ext_vector_type(8))) short short8;
typedef __attribute__((ext_vector_type(4))) float f32x4;

// ---- workspace layout (floats) ----
constexpr int OFF_P   = 0;                          // B*S*D
constexpr int OFF_Q   = OFF_P  + BB*SS*DD;          // B*S*D (Q' = desc@eW1[D:] + eb1)
constexpr int OFF_V   = OFF_Q  + BB*SS*DD;          // B*NS*D
constexpr int OFF_QA  = OFF_V  + BB*NSl*DD;         // B*NS*H
constexpr int OFF_KA  = OFF_QA + BB*NSl*HH;         // B*NS*H
constexpr int OFF_W2B = OFF_KA + BB*NSl*HH;         // 16*768 bf16 = 6144 floats
constexpr int OFF_WQA = OFF_W2B + 6144;             // H*D
constexpr int OFF_WKA = OFF_WQA + HH*DD;            // H*D
constexpr int OFF_BF  = OFF_WKA + HH*DD;            // 36
constexpr int OFF_SP  = OFF_BF + 64;                // B*128 each
constexpr int OFF_SSP = OFF_SP + BB*128;
constexpr int OFF_SQ  = OFF_SSP + BB*128;
constexpr int OFF_SSQ = OFF_SQ + BB*128;
constexpr int OFF_EL  = OFF_SSQ + BB*128;           // B*H*NS*NS

__device__ inline unsigned short f2bf(float f) {
    unsigned int u = __builtin_bit_cast(unsigned int, f);
    u += 0x7fffu + ((u >> 16) & 1u);
    return (unsigned short)(u >> 16);
}

__device__ inline short8 pack8(float4 a, float4 b) {
    short8 p;
    p[0] = (short)f2bf(a.x); p[1] = (short)f2bf(a.y);
    p[2] = (short)f2bf(a.z); p[3] = (short)f2bf(a.w);
    p[4] = (short)f2bf(b.x); p[5] = (short)f2bf(b.y);
    p[6] = (short)f2bf(b.z); p[7] = (short)f2bf(b.w);
    return p;
}

// unpack short8 (bf16) -> 8 floats
__device__ inline void unpack8(short8 s, float* f) {
    int4 u = __builtin_bit_cast(int4, s);
    f[0] = __builtin_bit_cast(float, u.x << 16);
    f[1] = __builtin_bit_cast(float, u.x & 0xffff0000);
    f[2] = __builtin_bit_cast(float, u.y << 16);
    f[3] = __builtin_bit_cast(float, u.y & 0xffff0000);
    f[4] = __builtin_bit_cast(float, u.z << 16);
    f[5] = __builtin_bit_cast(float, u.z & 0xffff0000);
    f[6] = __builtin_bit_cast(float, u.w << 16);
    f[7] = __builtin_bit_cast(float, u.w & 0xffff0000);
}

// ---------------------------------------------------------------------------
// Fold: W2B[h][c] (bf16, h padded to 16) = eW2[c, h*64+d]·ae; WQA/WKA; biases.
// ---------------------------------------------------------------------------
__global__ void fold_kernel(const float* __restrict__ Wq, const float* __restrict__ Wk,
                            const float* __restrict__ eW2,
                            const float* __restrict__ bq, const float* __restrict__ bk,
                            const float* __restrict__ eb2,
                            const float* __restrict__ aW,
                            unsigned short* __restrict__ W2Bu, float* __restrict__ WQA,
                            float* __restrict__ WKA, float* __restrict__ bfold) {
    int idx = blockIdx.x * 256 + threadIdx.x;
    const int total = 3 * HH * DD;
    if (idx < total) {
        int which = idx / (HH * DD);
        int r = idx % (HH * DD);
        int h = r / DD;
        int c = r % DD;
        const float* W = (which == 0) ? eW2 : (which == 1) ? Wq : Wk;
        const float* a = (which == 0) ? (aW + 2 * HDl) : (which == 1) ? aW : (aW + HDl);
        float s = 0.f;
        #pragma unroll 8
        for (int d = 0; d < HDl; ++d) s += W[c * DD + h * HDl + d] * a[d];
        if (which == 0) W2Bu[h * DD + c] = f2bf(s);
        else if (which == 1) WQA[h * DD + c] = s;
        else WKA[h * DD + c] = s;
    } else if (idx < total + 36) {
        int r = idx - total;
        int which = r / HH, h = r % HH;
        const float* bb = (which == 0) ? eb2 : (which == 1) ? bq : bk;
        const float* a = (which == 0) ? (aW + 2 * HDl) : (which == 1) ? aW : (aW + HDl);
        float s = 0.f;
        for (int d = 0; d < HDl; ++d) s += bb[h * HDl + d] * a[d];
        bfold[r] = s;
    } else if (idx < total + 36 + 4 * DD) {
        W2Bu[12 * DD + (idx - total - 36)] = 0;   // pad heads 12..15
    }
}

// ---------------------------------------------------------------------------
// MFMA bf16 GEMM: z=0: P=desc@eW1[:D]; z=1: Q'=desc@eW1[D:]+eb1; z=2: V=nve@Wv+bv
// ---------------------------------------------------------------------------
__global__ __launch_bounds__(256) void gemm3_mfma(
        const float* __restrict__ desc, const float* __restrict__ nve,
        const float* __restrict__ eW1, const float* __restrict__ Wv,
        const float* __restrict__ bv, const float* __restrict__ eb1,
        float* __restrict__ P, float* __restrict__ Qm, float* __restrict__ V) {
    const int z = blockIdx.z;
    const float* A    = (z == 2) ? nve : desc;
    const float* Bm   = (z == 0) ? eW1 : (z == 1) ? (eW1 + DD * DD) : Wv;
    const float* bias = (z == 0) ? nullptr : (z == 1) ? eb1 : bv;
    float* C          = (z == 0) ? P : (z == 1) ? Qm : V;
    const int M       = (z == 2) ? (BB * NSl) : (BB * SS);

    __shared__ short As[64 * 64];
    __shared__ short Bs[64 * 64];

    const int tid  = threadIdx.x;
    const int lane = tid & 63;
    const int w    = tid >> 6;
    const int wr   = w >> 1, wc = w & 1;
    const int brow = blockIdx.y * 64, bcol = blockIdx.x * 64;

    f32x4 acc[2][2] = {};

    for (int k0 = 0; k0 < DD; k0 += 64) {
        #pragma unroll
        for (int it = 0; it < 2; ++it) {
            int chunk = tid + it * 256;
            int row = chunk >> 3;
            int kc  = (chunk & 7) * 8;
            int gm  = brow + row;
            float4 f0 = {0,0,0,0}, f1 = {0,0,0,0};
            if (gm < M) {
                f0 = *(const float4*)(A + gm * DD + k0 + kc);
                f1 = *(const float4*)(A + gm * DD + k0 + kc + 4);
            }
            int byte = (row * 128 + kc * 2) ^ ((row & 7) << 4);
            *(short8*)((char*)As + byte) = pack8(f0, f1);
        }
        {
            int n = tid & 63, g = tid >> 6;
            unsigned short ub[16];
            #pragma unroll
            for (int q = 0; q < 16; ++q)
                ub[q] = f2bf(Bm[(k0 + g * 16 + q) * DD + bcol + n]);
            short8 p0, p1;
            #pragma unroll
            for (int q = 0; q < 8; ++q) { p0[q] = (short)ub[q]; p1[q] = (short)ub[q + 8]; }
            int base = n * 128 + g * 32;
            int sw   = (n & 7) << 4;
            *(short8*)((char*)Bs + (base ^ sw))        = p0;
            *(short8*)((char*)Bs + ((base + 16) ^ sw)) = p1;
        }
        __syncthreads();
        #pragma unroll
        for (int ks = 0; ks < 2; ++ks) {
            const int kb = ks * 64 + ((lane >> 4) << 4);
            short8 af[2], bfr[2];
            #pragma unroll
            for (int mi = 0; mi < 2; ++mi) {
                int row = wr * 32 + mi * 16 + (lane & 15);
                af[mi] = *(const short8*)((char*)As + ((row * 128 + kb) ^ ((row & 7) << 4)));
            }
            #pragma unroll
            for (int ni = 0; ni < 2; ++ni) {
                int col = wc * 32 + ni * 16 + (lane & 15);
                bfr[ni] = *(const short8*)((char*)Bs + ((col * 128 + kb) ^ ((col & 7) << 4)));
            }
            #pragma unroll
            for (int mi = 0; mi < 2; ++mi)
                #pragma unroll
                for (int ni = 0; ni < 2; ++ni)
                    acc[mi][ni] = __builtin_amdgcn_mfma_f32_16x16x32_bf16(
                        af[mi], bfr[ni], acc[mi][ni], 0, 0, 0);
        }
        __syncthreads();
    }
    #pragma unroll
    for (int mi = 0; mi < 2; ++mi)
        #pragma unroll
        for (int ni = 0; ni < 2; ++ni) {
            int gcol = bcol + wc * 32 + ni * 16 + (lane & 15);
            float badd = bias ? bias[gcol] : 0.f;
            #pragma unroll
            for (int r = 0; r < 4; ++r) {
                int grow = brow + wr * 32 + mi * 16 + ((lane >> 4) << 2) + r;
                if (grow < M) C[grow * DD + gcol] = acc[mi][ni][r] + badd;
            }
        }
}

// ---------------------------------------------------------------------------
// Merged rowstat + qk: one wave per task.
// ---------------------------------------------------------------------------
__global__ void statqk_kernel(const float* __restrict__ Pp, const float* __restrict__ Qp,
                              const float* __restrict__ nve,
                              const float* __restrict__ WQA, const float* __restrict__ WKA,
                              const float* __restrict__ bfold,
                              float* __restrict__ SP, float* __restrict__ SSP,
                              float* __restrict__ SQ, float* __restrict__ SSQ,
                              float* __restrict__ qa, float* __restrict__ ka) {
    int wid = blockIdx.x * 4 + (threadIdx.x >> 6);
    int lane = threadIdx.x & 63;
    const int NSTAT = BB * SS * 2;
    if (wid < NSTAT) {
        int which = wid & 1;
        int row = (wid >> 1) % SS;
        int b = (wid >> 1) / SS;
        const float* src = (which ? Qp : Pp) + (b * SS + row) * DD;
        float s = 0.f, ss = 0.f;
        #pragma unroll
        for (int r = 0; r < 12; ++r) {
            float v = src[lane + 64 * r];
            s += v;
            ss += v * v;
        }
        #pragma unroll
        for (int off = 32; off; off >>= 1) {
            s += __shfl_xor(s, off);
            ss += __shfl_xor(ss, off);
        }
        if (lane == 0) {
            (which ? SQ : SP)[b * 128 + row] = s;
            (which ? SSQ : SSP)[b * 128 + row] = ss;
        }
    } else {
        int t2 = wid - NSTAT;
        if (t2 >= BB * NSl * HH * 2) return;
        int which = t2 & 1;
        int r = t2 >> 1;
        int h = r % HH;
        int t = (r / HH) % NSl;
        int b = r / (HH * NSl);
        const float* W = (which ? WKA : WQA) + h * DD;
        const float* row = nve + (b * NSl + t) * DD;
        float s = 0.f;
        #pragma unroll
        for (int rr = 0; rr < 12; ++rr) {
            int c = lane + 64 * rr;
            s += row[c] * W[c];
        }
        #pragma unroll
        for (int off = 32; off; off >>= 1) s += __shfl_xor(s, off);
        if (lane == 0)
            (which ? ka : qa)[(b * NSl + t) * HH + h] = s + bfold[12 + which * 12 + h];
    }
}

// ---------------------------------------------------------------------------
// Pair MFMA v2: block = (b, 16x16 pi/qj tile), 512 threads (8 waves).
// ---------------------------------------------------------------------------
__global__ __launch_bounds__(512) void pair_mfma(
        const float* __restrict__ Pp, const float* __restrict__ Qp,
        const float* __restrict__ ln_g, const float* __restrict__ ln_b,
        const unsigned short* __restrict__ W2Bu,
        const float* __restrict__ SP, const float* __restrict__ SSP,
        const float* __restrict__ SQ, const float* __restrict__ SSQ,
        const float* __restrict__ bfold,
        float* __restrict__ e_log) {
    __shared__ short pB[16 * 768];    // 24KB
    __shared__ short qB[16 * 768];    // 24KB
    __shared__ float gbl[2 * 768];    // 6KB: [0..767]=ln_g, [768..1535]=ln_b

    const int b   = blockIdx.z;
    const int pi0 = blockIdx.y * 16, qj0 = blockIdx.x * 16;
    const int tid = threadIdx.x;

    // ---- stage P,Q rows (bf16, swizzled) ----
    {
        int row = tid >> 5;               // 0..15
        int ccb = tid & 31;
        const float* psrc = Pp + (b * SS + min(pi0 + row, SS - 1)) * DD;
        const float* qsrc = Qp + (b * SS + min(qj0 + row, SS - 1)) * DD;
        #pragma unroll
        for (int it = 0; it < 3; ++it) {
            int cc = ccb + it * 32;       // 0..95
            int byte = (row * 1536 + cc * 16) ^ ((row & 7) << 4);
            float4 a0 = *(const float4*)(psrc + cc * 8);
            float4 a1 = *(const float4*)(psrc + cc * 8 + 4);
            *(short8*)((char*)pB + byte) = pack8(a0, a1);
            a0 = *(const float4*)(qsrc + cc * 8);
            a1 = *(const float4*)(qsrc + cc * 8 + 4);
            *(short8*)((char*)qB + byte) = pack8(a0, a1);
        }
    }
    if (tid < 384) {
        int c = tid * 4;
        float4 v = (tid < 192) ? *(const float4*)(ln_g + c)
                               : *(const float4*)(ln_b + (c - 768));
        *(float4*)(gbl + c) = v;
    }
    __syncthreads();

    const int lane = tid & 63;
    const int w    = tid >> 6;
    const int l15  = lane & 15;
    const int kg   = lane >> 4;

    // ---- in-block Gram: G[pi_loc][qj_loc], C-frag in regs ----
    f32x4 gacc = {};
    #pragma unroll 4
    for (int ks = 0; ks < 24; ++ks) {
        int cb = ks * 64 + kg * 16;
        short8 ap = *(const short8*)((char*)pB + ((l15 * 1536 + cb) ^ ((l15 & 7) << 4)));
        short8 aq = *(const short8*)((char*)qB + ((l15 * 1536 + cb) ^ ((l15 & 7) << 4)));
        gacc = __builtin_amdgcn_mfma_f32_16x16x32_bf16(ap, aq, gacc, 0, 0, 0);
    }

    // ---- per-pair LN scalars for this wave's two pi rows ----
    float al[2], be[2];
    #pragma unroll
    for (int s = 0; s < 2; ++s) {
        int pl = 2 * w + s;
        int src = ((pl >> 2) << 4) | l15;
        int rsel = pl & 3;
        float gg = (rsel == 0) ? gacc[0] : (rsel == 1) ? gacc[1]
                 : (rsel == 2) ? gacc[2] : gacc[3];
        gg = __shfl(gg, src);
        int pig = min(pi0 + pl, SS - 1);
        int qjg = min(qj0 + l15, SS - 1);
        float mean = (SP[b * 128 + pig] + SQ[b * 128 + qjg]) * (1.f / DD);
        float sumsq = SSP[b * 128 + pig] + 2.f * gg + SSQ[b * 128 + qjg];
        float var = sumsq * (1.f / DD) - mean * mean;
        float a = rsqrtf(var + 1e-5f);
        al[s] = a;
        be[s] = -mean * a;
    }

    // ---- main loop over channels ----
    const unsigned short* wrow = W2Bu + l15 * 768;
    const int r0 = 2 * w, r1 = 2 * w + 1;
    const int p0base = r0 * 1536, p1base = r1 * 1536;
    const int p0x = (r0 & 7) << 4, p1x = (r1 & 7) << 4;
    f32x4 acc0 = {}, acc1 = {};

    #pragma unroll 2
    for (int ks = 0; ks < 24; ++ks) {
        const int c0 = ks * 32 + kg * 8;
        short8 bfg = *(const short8*)(wrow + c0);
        f32x4 g0 = *(const f32x4*)(gbl + c0);
        f32x4 g1 = *(const f32x4*)(gbl + c0 + 4);
        f32x4 bb0 = *(const f32x4*)(gbl + 768 + c0);
        f32x4 bb1 = *(const f32x4*)(gbl + 768 + c0 + 4);
        float gv[8] = {g0.x, g0.y, g0.z, g0.w, g1.x, g1.y, g1.z, g1.w};
        float bv8[8] = {bb0.x, bb0.y, bb0.z, bb0.w, bb1.x, bb1.y, bb1.z, bb1.w};

        short8 q8 = *(const short8*)((char*)qB + ((l15 * 1536 + c0 * 2) ^ ((l15 & 7) << 4)));
        float qf[8];
        unpack8(q8, qf);

        short8 p8 = *(const short8*)((char*)pB + ((p0base + c0 * 2) ^ p0x));
        float pf[8];
        unpack8(p8, pf);
        short8 ya;
        #pragma unroll
        for (int j = 0; j < 8; ++j) {
            float t = pf[j] + qf[j];
            float u = __builtin_fmaf(al[0], t, be[0]);
            float y = fmaxf(__builtin_fmaf(gv[j], u, bv8[j]), 0.f);
            ya[j] = (short)f2bf(y);
        }
        acc0 = __builtin_amdgcn_mfma_f32_16x16x32_bf16(ya, bfg, acc0, 0, 0, 0);

        p8 = *(const short8*)((char*)pB + ((p1base + c0 * 2) ^ p1x));
        unpack8(p8, pf);
        #pragma unroll
        for (int j = 0; j < 8; ++j) {
            float t = pf[j] + qf[j];
            float u = __builtin_fmaf(al[1], t, be[1]);
            float y = fmaxf(__builtin_fmaf(gv[j], u, bv8[j]), 0.f);
            ya[j] = (short)f2bf(y);
        }
        acc1 = __builtin_amdgcn_mfma_f32_16x16x32_bf16(ya, bfg, acc1, 0, 0, 0);
    }

    // ---- epilogue: C-frag row=(kg*4+r)=qj_loc, col=l15=head ----
    if (l15 < HH) {
        const float badd = bfold[l15];
        #pragma unroll
        for (int s = 0; s < 2; ++s) {
            int pig = pi0 + 2 * w + s;
            if (pig >= SS) continue;
            f32x4 A = s ? acc1 : acc0;
            #pragma unroll
            for (int r = 0; r < 4; ++r) {
                int qjg = qj0 + (kg << 2) + r;
                if (qjg < SS) {
                    int i = (pig == qjg) ? 0 : (pig + 1);
                    e_log[(((b * HH + l15) * NSl) + i) * NSl + (qjg + 1)] = A[r] + badd;
                }
            }
        }
    }
}

// ---------------------------------------------------------------------------
// Softmax + context v2: block = (iq, h, b), 512 threads (8 waves).
// attn written directly from registers (no LDS round-trip — avoids the
// lane-local-alias reorder race); pl[] + __syncthreads() for the context dot.
// ---------------------------------------------------------------------------
__global__ __launch_bounds__(512) void softmax_ctx_kernel(
        const float* __restrict__ e_log,
        const float* __restrict__ qa, const float* __restrict__ ka,
        const float* __restrict__ mask_M, const float* __restrict__ ab,
        const float* __restrict__ V,
        float* __restrict__ out) {
    __shared__ float Vl[NSl * HDl];   // 32KB [j][d]
    __shared__ float kal[NSl];
    __shared__ float pl[8][NSl];      // 4KB, per-wave

    const int b = blockIdx.z;
    const int h = blockIdx.y;
    const int iq = blockIdx.x;
    const int tid = threadIdx.x;
    const int lane = tid & 63;
    const int w = tid >> 6;

    #pragma unroll
    for (int it = 0; it < 4; ++it) {
        int m = tid + it * 512;            // 0..2047 float4 chunks
        int j = m >> 4, dd = (m & 15) * 4;
        *(float4*)(Vl + j * HDl + dd) =
            *(const float4*)(V + (b * NSl + j) * DD + h * HDl + dd);
    }
    if (tid < NSl) kal[tid] = ka[(b * NSl + tid) * HH + h];
    __syncthreads();

    const float abv = ab[0];

    for (int rr = 0; rr < 4; ++rr) {
        const int i = iq * 32 + w * 4 + rr;
        const float qv = qa[(b * NSl + i) * HH + h];
        const float* e_row = e_log + (((b * HH + h) * NSl) + i) * NSl;

        float lg[2];
        bool valid[2];
        #pragma unroll
        for (int s = 0; s < 2; ++s) {
            int j = 1 + lane + 64 * s;
            bool v = (j < NSl) && !(i >= 1 && j == i);
            float l = -1e30f;
            if (v) {
                l = e_row[j] + qv + kal[j] + abv;
                if (i >= 1) {
                    float p = mask_M[((b * HH + h) * SS + (i - 1)) * SS + (j - 1)];
                    p = fminf(fmaxf(p, 1e-6f), 1.0f - 1e-6f);
                    l += __logf(p) - __logf(1.0f - p);
                }
            }
            lg[s] = l;
            valid[s] = v;
        }
        float m = fmaxf(lg[0], lg[1]);
        #pragma unroll
        for (int off = 32; off; off >>= 1) m = fmaxf(m, __shfl_xor(m, off));
        float e0 = valid[0] ? __expf(lg[0] - m) : 0.f;
        float e1 = valid[1] ? __expf(lg[1] - m) : 0.f;
        float s = e0 + e1;
        #pragma unroll
        for (int off = 32; off; off >>= 1) s += __shfl_xor(s, off);
        const float inv = 1.0f / s;

        const float p0 = e0 * inv, p1 = e1 * inv;

        // attn straight from registers: slot 1+lane <- p0, slot 65+lane <- p1
        float* attn_row = out + BB * NSl * HH * HDl + (((b * HH + h) * NSl) + i) * NSl;
        attn_row[1 + lane] = p0;
        if (65 + lane < NSl) attn_row[65 + lane] = p1;
        if (lane == 0) attn_row[0] = 0.f;

        pl[w][1 + lane] = p0;
        if (65 + lane < NSl) pl[w][65 + lane] = p1;
        if (lane == 0) pl[w][0] = 0.f;
        __syncthreads();   // order cross-lane LDS writes before the dot

        float c0 = 0.f, c1 = 0.f, c2 = 0.f, c3 = 0.f;
        #pragma unroll 4
        for (int j = 0; j < NSl; j += 4) {
            c0 += pl[w][j]     * Vl[(j)     * HDl + lane];
            c1 += pl[w][j + 1] * Vl[(j + 1) * HDl + lane];
            c2 += pl[w][j + 2] * Vl[(j + 2) * HDl + lane];
            c3 += pl[w][j + 3] * Vl[(j + 3) * HDl + lane];
        }
        out[((b * NSl + i) * HH + h) * HDl + lane] = (c0 + c1) + (c2 + c3);
        __syncthreads();   // protect pl against next iteration's writes
    }
}

// ---------------------------------------------------------------------------
extern "C" void kernel_launch(void* const* d_in, const int* in_sizes, int n_in,
                              void* d_out, int out_size, void* d_ws, size_t ws_size,
                              hipStream_t stream) {
    const float* desc   = (const float*)d_in[0];
    const float* nve    = (const float*)d_in[1];
    const float* mask_M = (const float*)d_in[2];
    const float* Wq     = (const float*)d_in[3];
    const float* bq     = (const float*)d_in[4];
    const float* Wk     = (const float*)d_in[5];
    const float* bk     = (const float*)d_in[6];
    const float* Wv     = (const float*)d_in[7];
    const float* bv     = (const float*)d_in[8];
    const float* eW1    = (const float*)d_in[9];
    const float* eb1    = (const float*)d_in[10];
    const float* ln_g   = (const float*)d_in[11];
    const float* ln_b   = (const float*)d_in[12];
    const float* eW2    = (const float*)d_in[13];
    const float* eb2    = (const float*)d_in[14];
    const float* aW     = (const float*)d_in[15];
    const float* ab     = (const float*)d_in[16];

    float* ws  = (float*)d_ws;
    float* out = (float*)d_out;
    unsigned short* W2Bu = (unsigned short*)(ws + OFF_W2B);

    fold_kernel<<<(3 * HH * DD + 36 + 4 * DD + 255) / 256, 256, 0, stream>>>(
        Wq, Wk, eW2, bq, bk, eb2, aW,
        W2Bu, ws + OFF_WQA, ws + OFF_WKA, ws + OFF_BF);

    gemm3_mfma<<<dim3(DD / 64, (BB * NSl + 63) / 64, 3), 256, 0, stream>>>(
        desc, nve, eW1, Wv, bv, eb1, ws + OFF_P, ws + OFF_Q, ws + OFF_V);

    statqk_kernel<<<(BB * SS * 2 + BB * NSl * HH * 2 + 3) / 4, 256, 0, stream>>>(
        ws + OFF_P, ws + OFF_Q, nve, ws + OFF_WQA, ws + OFF_WKA, ws + OFF_BF,
        ws + OFF_SP, ws + OFF_SSP, ws + OFF_SQ, ws + OFF_SSQ,
        ws + OFF_QA, ws + OFF_KA);

    pair_mfma<<<dim3(8, 8, BB), 512, 0, stream>>>(
        ws + OFF_P, ws + OFF_Q, ln_g, ln_b, W2Bu,
        ws + OFF_SP, ws + OFF_SSP, ws + OFF_SQ, ws + OFF_SSQ,
        ws + OFF_BF, ws + OFF_EL);

    softmax_ctx_kernel<<<dim3(4, HH, BB), 512, 0, stream>>>(
        ws + OFF_EL, ws + OFF_QA, ws + OFF_KA, mask_M, ab, ws + OFF_V, out);
}

// Round 6
// 64.179 us; speedup vs baseline: 4.5611x; 1.0625x over previous
//
#include <hip/hip_runtime.h>
#include <hip/hip_bf16.h>

#define BB  4
#define SS  127
#define DD  768
#define HH  12
#define HDl 64
#define NSl 128

typedef __attribute__((ext_vector_type(8))) short short8;
typedef __attribute__((ext_vector_type(4))) float f32x4;

// ---- workspace layout (floats) ----
constexpr int OFF_P   = 0;                          // B*S*D
constexpr int OFF_Q   = OFF_P  + BB*SS*DD;          // B*S*D (Q' = desc@eW1[D:] + eb1)
constexpr int OFF_V   = OFF_Q  + BB*SS*DD;          // B*NS*D
constexpr int OFF_QA  = OFF_V  + BB*NSl*DD;         // B*NS*H
constexpr int OFF_KA  = OFF_QA + BB*NSl*HH;         // B*NS*H
constexpr int OFF_W2B = OFF_KA + BB*NSl*HH;         // 16*768 bf16 = 6144 floats
constexpr int OFF_WQA = OFF_W2B + 6144;             // H*D
constexpr int OFF_WKA = OFF_WQA + HH*DD;            // H*D
constexpr int OFF_BF  = OFF_WKA + HH*DD;            // 36
constexpr int OFF_SP  = OFF_BF + 64;                // B*128 each
constexpr int OFF_SSP = OFF_SP + BB*128;
constexpr int OFF_SQ  = OFF_SSP + BB*128;
constexpr int OFF_SSQ = OFF_SQ + BB*128;
constexpr int OFF_EL  = OFF_SSQ + BB*128;           // B*H*NS*NS

__device__ inline unsigned short f2bf(float f) {
    unsigned int u = __builtin_bit_cast(unsigned int, f);
    u += 0x7fffu + ((u >> 16) & 1u);
    return (unsigned short)(u >> 16);
}

__device__ inline short8 pack8(float4 a, float4 b) {
    short8 p;
    p[0] = (short)f2bf(a.x); p[1] = (short)f2bf(a.y);
    p[2] = (short)f2bf(a.z); p[3] = (short)f2bf(a.w);
    p[4] = (short)f2bf(b.x); p[5] = (short)f2bf(b.y);
    p[6] = (short)f2bf(b.z); p[7] = (short)f2bf(b.w);
    return p;
}

// unpack short8 (bf16) -> 8 floats
__device__ inline void unpack8(short8 s, float* f) {
    int4 u = __builtin_bit_cast(int4, s);
    f[0] = __builtin_bit_cast(float, u.x << 16);
    f[1] = __builtin_bit_cast(float, u.x & 0xffff0000);
    f[2] = __builtin_bit_cast(float, u.y << 16);
    f[3] = __builtin_bit_cast(float, u.y & 0xffff0000);
    f[4] = __builtin_bit_cast(float, u.z << 16);
    f[5] = __builtin_bit_cast(float, u.z & 0xffff0000);
    f[6] = __builtin_bit_cast(float, u.w << 16);
    f[7] = __builtin_bit_cast(float, u.w & 0xffff0000);
}

// ---------------------------------------------------------------------------
// MEGA1: one launch, role-dispatched.
//   blocks [0,96):    PQ GEMM tiles (bx=r%12 col-tile, by=r/12 row-tile):
//                     P = desc@eW1[:D], Q' = desc@eW1[D:]+eb1 (shared A stage)
//   blocks [96,192):  V GEMM tiles: V = nve@Wv+bv
//   blocks [192,253): fold (W2B/WQA/WKA/biases)
// GEMM: 64x64 tile, 512 thr (8 waves, wave=16x32), reg-prefetch next K-slab.
// ---------------------------------------------------------------------------
constexpr int NB_PQ   = 96;
constexpr int NB_V    = 96;
constexpr int FOLD_T  = 3 * HH * DD + 36 + 4 * DD;   // 30756
constexpr int NB_FOLD = (FOLD_T + 511) / 512;        // 61

__global__ __launch_bounds__(512) void mega1(
        const float* __restrict__ desc, const float* __restrict__ nve,
        const float* __restrict__ eW1, const float* __restrict__ Wv,
        const float* __restrict__ bv, const float* __restrict__ eb1,
        const float* __restrict__ Wq, const float* __restrict__ Wk,
        const float* __restrict__ eW2,
        const float* __restrict__ bq, const float* __restrict__ bk,
        const float* __restrict__ eb2, const float* __restrict__ aW,
        float* __restrict__ P, float* __restrict__ Qm, float* __restrict__ V,
        unsigned short* __restrict__ W2Bu, float* __restrict__ WQA,
        float* __restrict__ WKA, float* __restrict__ bfold) {
    const int bid = blockIdx.x;
    const int tid = threadIdx.x;

    if (bid >= NB_PQ + NB_V) {
        // ---------------- fold role ----------------
        int idx = (bid - NB_PQ - NB_V) * 512 + tid;
        const int total = 3 * HH * DD;
        if (idx < total) {
            int which = idx / (HH * DD);
            int r = idx % (HH * DD);
            int h = r / DD;
            int c = r % DD;
            const float* W = (which == 0) ? eW2 : (which == 1) ? Wq : Wk;
            const float* a = (which == 0) ? (aW + 2 * HDl) : (which == 1) ? aW : (aW + HDl);
            float s = 0.f;
            #pragma unroll 8
            for (int d = 0; d < HDl; ++d) s += W[c * DD + h * HDl + d] * a[d];
            if (which == 0) W2Bu[h * DD + c] = f2bf(s);
            else if (which == 1) WQA[h * DD + c] = s;
            else WKA[h * DD + c] = s;
        } else if (idx < total + 36) {
            int r = idx - total;
            int which = r / HH, h = r % HH;
            const float* bb = (which == 0) ? eb2 : (which == 1) ? bq : bk;
            const float* a = (which == 0) ? (aW + 2 * HDl) : (which == 1) ? aW : (aW + HDl);
            float s = 0.f;
            for (int d = 0; d < HDl; ++d) s += bb[h * HDl + d] * a[d];
            bfold[r] = s;
        } else if (idx < FOLD_T) {
            W2Bu[12 * DD + (idx - total - 36)] = 0;   // pad heads 12..15
        }
        return;
    }

    // ---------------- GEMM roles ----------------
    const bool pq = (bid < NB_PQ);
    const int r = pq ? bid : bid - NB_PQ;
    const int bcol = (r % 12) * 64;
    const int brow = (r / 12) * 64;
    const float* A  = pq ? desc : nve;
    const float* B0 = pq ? eW1 : Wv;
    const int M = pq ? (BB * SS) : (BB * NSl);

    __shared__ short lds[3 * 64 * 64];   // As | Bs0 | Bs1
    short* As  = lds;
    short* Bs0 = lds + 4096;
    short* Bs1 = lds + 8192;

    const int arow = tid >> 3, akc = (tid & 7) * 8;
    const int abyte = (arow * 128 + akc * 2) ^ ((arow & 7) << 4);
    const int bn = tid & 63, bg = tid >> 6;
    const int bbyte = (bn * 128 + bg * 16) ^ ((bn & 7) << 4);

    const int gm = brow + arow;
    const float* arow_p = A + gm * DD + akc;

    short8 gA, gB0, gB1;
    auto loadA = [&](int k0) {
        float4 f0 = {0,0,0,0}, f1 = {0,0,0,0};
        if (gm < M) {
            f0 = *(const float4*)(arow_p + k0);
            f1 = *(const float4*)(arow_p + k0 + 4);
        }
        gA = pack8(f0, f1);
    };
    auto loadB = [&](const float* Bm, int k0, short8& dst) {
        float v[8];
        #pragma unroll
        for (int q = 0; q < 8; ++q)
            v[q] = Bm[(k0 + bg * 8 + q) * DD + bcol + bn];
        short8 p;
        #pragma unroll
        for (int q = 0; q < 8; ++q) p[q] = (short)f2bf(v[q]);
        dst = p;
    };

    loadA(0);
    loadB(B0, 0, gB0);
    if (pq) loadB(eW1 + DD * DD, 0, gB1);

    const int lane = tid & 63;
    const int w = tid >> 6;
    const int wr = w >> 1, wc = w & 1;
    const int l15 = lane & 15;

    f32x4 acc0[2] = {};   // B0 output (P or V)
    f32x4 acc1[2] = {};   // B1 output (Q), pq only

    for (int k0 = 0; k0 < DD; k0 += 64) {
        *(short8*)((char*)As + abyte) = gA;
        *(short8*)((char*)Bs0 + bbyte) = gB0;
        if (pq) *(short8*)((char*)Bs1 + bbyte) = gB1;
        __syncthreads();
        if (k0 + 64 < DD) {
            loadA(k0 + 64);
            loadB(B0, k0 + 64, gB0);
            if (pq) loadB(eW1 + DD * DD, k0 + 64, gB1);
        }
        #pragma unroll
        for (int ks = 0; ks < 2; ++ks) {
            const int kb = ks * 64 + ((lane >> 4) << 4);
            int row = wr * 16 + l15;
            short8 af = *(const short8*)((char*)As + ((row * 128 + kb) ^ ((row & 7) << 4)));
            #pragma unroll
            for (int ni = 0; ni < 2; ++ni) {
                int col = wc * 32 + ni * 16 + l15;
                int cb = (col * 128 + kb) ^ ((col & 7) << 4);
                short8 b0 = *(const short8*)((char*)Bs0 + cb);
                acc0[ni] = __builtin_amdgcn_mfma_f32_16x16x32_bf16(af, b0, acc0[ni], 0, 0, 0);
                if (pq) {
                    short8 b1 = *(const short8*)((char*)Bs1 + cb);
                    acc1[ni] = __builtin_amdgcn_mfma_f32_16x16x32_bf16(af, b1, acc1[ni], 0, 0, 0);
                }
            }
        }
        __syncthreads();
    }

    #pragma unroll
    for (int ni = 0; ni < 2; ++ni) {
        int gcol = bcol + wc * 32 + ni * 16 + l15;
        float bias0 = pq ? 0.f : bv[gcol];
        float bias1 = pq ? eb1[gcol] : 0.f;
        #pragma unroll
        for (int rr = 0; rr < 4; ++rr) {
            int grow = brow + wr * 16 + ((lane >> 4) << 2) + rr;
            if (grow < M) {
                if (pq) {
                    P[grow * DD + gcol]  = acc0[ni][rr];
                    Qm[grow * DD + gcol] = acc1[ni][rr] + bias1;
                } else {
                    V[grow * DD + gcol] = acc0[ni][rr] + bias0;
                }
            }
        }
    }
}

// ---------------------------------------------------------------------------
// Merged rowstat + qk: one wave per task.
// ---------------------------------------------------------------------------
__global__ void statqk_kernel(const float* __restrict__ Pp, const float* __restrict__ Qp,
                              const float* __restrict__ nve,
                              const float* __restrict__ WQA, const float* __restrict__ WKA,
                              const float* __restrict__ bfold,
                              float* __restrict__ SP, float* __restrict__ SSP,
                              float* __restrict__ SQ, float* __restrict__ SSQ,
                              float* __restrict__ qa, float* __restrict__ ka) {
    int wid = blockIdx.x * 4 + (threadIdx.x >> 6);
    int lane = threadIdx.x & 63;
    const int NSTAT = BB * SS * 2;
    if (wid < NSTAT) {
        int which = wid & 1;
        int row = (wid >> 1) % SS;
        int b = (wid >> 1) / SS;
        const float* src = (which ? Qp : Pp) + (b * SS + row) * DD;
        float s = 0.f, ss = 0.f;
        #pragma unroll
        for (int r = 0; r < 12; ++r) {
            float v = src[lane + 64 * r];
            s += v;
            ss += v * v;
        }
        #pragma unroll
        for (int off = 32; off; off >>= 1) {
            s += __shfl_xor(s, off);
            ss += __shfl_xor(ss, off);
        }
        if (lane == 0) {
            (which ? SQ : SP)[b * 128 + row] = s;
            (which ? SSQ : SSP)[b * 128 + row] = ss;
        }
    } else {
        int t2 = wid - NSTAT;
        if (t2 >= BB * NSl * HH * 2) return;
        int which = t2 & 1;
        int r = t2 >> 1;
        int h = r % HH;
        int t = (r / HH) % NSl;
        int b = r / (HH * NSl);
        const float* W = (which ? WKA : WQA) + h * DD;
        const float* row = nve + (b * NSl + t) * DD;
        float s = 0.f;
        #pragma unroll
        for (int rr = 0; rr < 12; ++rr) {
            int c = lane + 64 * rr;
            s += row[c] * W[c];
        }
        #pragma unroll
        for (int off = 32; off; off >>= 1) s += __shfl_xor(s, off);
        if (lane == 0)
            (which ? ka : qa)[(b * NSl + t) * HH + h] = s + bfold[12 + which * 12 + h];
    }
}

// ---------------------------------------------------------------------------
// Pair MFMA: block = (b, 16x16 pi/qj tile), 512 threads (8 waves).
// ---------------------------------------------------------------------------
__global__ __launch_bounds__(512) void pair_mfma(
        const float* __restrict__ Pp, const float* __restrict__ Qp,
        const float* __restrict__ ln_g, const float* __restrict__ ln_b,
        const unsigned short* __restrict__ W2Bu,
        const float* __restrict__ SP, const float* __restrict__ SSP,
        const float* __restrict__ SQ, const float* __restrict__ SSQ,
        const float* __restrict__ bfold,
        float* __restrict__ e_log) {
    __shared__ short pB[16 * 768];    // 24KB
    __shared__ short qB[16 * 768];    // 24KB
    __shared__ float gbl[2 * 768];    // 6KB

    const int b   = blockIdx.z;
    const int pi0 = blockIdx.y * 16, qj0 = blockIdx.x * 16;
    const int tid = threadIdx.x;

    {
        int row = tid >> 5;
        int ccb = tid & 31;
        const float* psrc = Pp + (b * SS + min(pi0 + row, SS - 1)) * DD;
        const float* qsrc = Qp + (b * SS + min(qj0 + row, SS - 1)) * DD;
        #pragma unroll
        for (int it = 0; it < 3; ++it) {
            int cc = ccb + it * 32;
            int byte = (row * 1536 + cc * 16) ^ ((row & 7) << 4);
            float4 a0 = *(const float4*)(psrc + cc * 8);
            float4 a1 = *(const float4*)(psrc + cc * 8 + 4);
            *(short8*)((char*)pB + byte) = pack8(a0, a1);
            a0 = *(const float4*)(qsrc + cc * 8);
            a1 = *(const float4*)(qsrc + cc * 8 + 4);
            *(short8*)((char*)qB + byte) = pack8(a0, a1);
        }
    }
    if (tid < 384) {
        int c = tid * 4;
        float4 v = (tid < 192) ? *(const float4*)(ln_g + c)
                               : *(const float4*)(ln_b + (c - 768));
        *(float4*)(gbl + c) = v;
    }
    __syncthreads();

    const int lane = tid & 63;
    const int w    = tid >> 6;
    const int l15  = lane & 15;
    const int kg   = lane >> 4;

    f32x4 gacc = {};
    #pragma unroll 4
    for (int ks = 0; ks < 24; ++ks) {
        int cb = ks * 64 + kg * 16;
        short8 ap = *(const short8*)((char*)pB + ((l15 * 1536 + cb) ^ ((l15 & 7) << 4)));
        short8 aq = *(const short8*)((char*)qB + ((l15 * 1536 + cb) ^ ((l15 & 7) << 4)));
        gacc = __builtin_amdgcn_mfma_f32_16x16x32_bf16(ap, aq, gacc, 0, 0, 0);
    }

    float al[2], be[2];
    #pragma unroll
    for (int s = 0; s < 2; ++s) {
        int pl = 2 * w + s;
        int src = ((pl >> 2) << 4) | l15;
        int rsel = pl & 3;
        float gg = (rsel == 0) ? gacc[0] : (rsel == 1) ? gacc[1]
                 : (rsel == 2) ? gacc[2] : gacc[3];
        gg = __shfl(gg, src);
        int pig = min(pi0 + pl, SS - 1);
        int qjg = min(qj0 + l15, SS - 1);
        float mean = (SP[b * 128 + pig] + SQ[b * 128 + qjg]) * (1.f / DD);
        float sumsq = SSP[b * 128 + pig] + 2.f * gg + SSQ[b * 128 + qjg];
        float var = sumsq * (1.f / DD) - mean * mean;
        float a = rsqrtf(var + 1e-5f);
        al[s] = a;
        be[s] = -mean * a;
    }

    const unsigned short* wrow = W2Bu + l15 * 768;
    const int r0 = 2 * w, r1 = 2 * w + 1;
    const int p0base = r0 * 1536, p1base = r1 * 1536;
    const int p0x = (r0 & 7) << 4, p1x = (r1 & 7) << 4;
    f32x4 acc0 = {}, acc1 = {};

    #pragma unroll 2
    for (int ks = 0; ks < 24; ++ks) {
        const int c0 = ks * 32 + kg * 8;
        short8 bfg = *(const short8*)(wrow + c0);
        f32x4 g0 = *(const f32x4*)(gbl + c0);
        f32x4 g1 = *(const f32x4*)(gbl + c0 + 4);
        f32x4 bb0 = *(const f32x4*)(gbl + 768 + c0);
        f32x4 bb1 = *(const f32x4*)(gbl + 768 + c0 + 4);
        float gv[8] = {g0.x, g0.y, g0.z, g0.w, g1.x, g1.y, g1.z, g1.w};
        float bv8[8] = {bb0.x, bb0.y, bb0.z, bb0.w, bb1.x, bb1.y, bb1.z, bb1.w};

        short8 q8 = *(const short8*)((char*)qB + ((l15 * 1536 + c0 * 2) ^ ((l15 & 7) << 4)));
        float qf[8];
        unpack8(q8, qf);

        short8 p8 = *(const short8*)((char*)pB + ((p0base + c0 * 2) ^ p0x));
        float pf[8];
        unpack8(p8, pf);
        short8 ya;
        #pragma unroll
        for (int j = 0; j < 8; ++j) {
            float t = pf[j] + qf[j];
            float u = __builtin_fmaf(al[0], t, be[0]);
            float y = fmaxf(__builtin_fmaf(gv[j], u, bv8[j]), 0.f);
            ya[j] = (short)f2bf(y);
        }
        acc0 = __builtin_amdgcn_mfma_f32_16x16x32_bf16(ya, bfg, acc0, 0, 0, 0);

        p8 = *(const short8*)((char*)pB + ((p1base + c0 * 2) ^ p1x));
        unpack8(p8, pf);
        #pragma unroll
        for (int j = 0; j < 8; ++j) {
            float t = pf[j] + qf[j];
            float u = __builtin_fmaf(al[1], t, be[1]);
            float y = fmaxf(__builtin_fmaf(gv[j], u, bv8[j]), 0.f);
            ya[j] = (short)f2bf(y);
        }
        acc1 = __builtin_amdgcn_mfma_f32_16x16x32_bf16(ya, bfg, acc1, 0, 0, 0);
    }

    if (l15 < HH) {
        const float badd = bfold[l15];
        #pragma unroll
        for (int s = 0; s < 2; ++s) {
            int pig = pi0 + 2 * w + s;
            if (pig >= SS) continue;
            f32x4 A = s ? acc1 : acc0;
            #pragma unroll
            for (int r = 0; r < 4; ++r) {
                int qjg = qj0 + (kg << 2) + r;
                if (qjg < SS) {
                    int i = (pig == qjg) ? 0 : (pig + 1);
                    e_log[(((b * HH + l15) * NSl) + i) * NSl + (qjg + 1)] = A[r] + badd;
                }
            }
        }
    }
}

// ---------------------------------------------------------------------------
// Softmax + context: block = (iq, h, b), 512 threads (8 waves).
// ---------------------------------------------------------------------------
__global__ __launch_bounds__(512) void softmax_ctx_kernel(
        const float* __restrict__ e_log,
        const float* __restrict__ qa, const float* __restrict__ ka,
        const float* __restrict__ mask_M, const float* __restrict__ ab,
        const float* __restrict__ V,
        float* __restrict__ out) {
    __shared__ float Vl[NSl * HDl];
    __shared__ float kal[NSl];
    __shared__ float pl[8][NSl];

    const int b = blockIdx.z;
    const int h = blockIdx.y;
    const int iq = blockIdx.x;
    const int tid = threadIdx.x;
    const int lane = tid & 63;
    const int w = tid >> 6;

    #pragma unroll
    for (int it = 0; it < 4; ++it) {
        int m = tid + it * 512;
        int j = m >> 4, dd = (m & 15) * 4;
        *(float4*)(Vl + j * HDl + dd) =
            *(const float4*)(V + (b * NSl + j) * DD + h * HDl + dd);
    }
    if (tid < NSl) kal[tid] = ka[(b * NSl + tid) * HH + h];
    __syncthreads();

    const float abv = ab[0];

    for (int rr = 0; rr < 4; ++rr) {
        const int i = iq * 32 + w * 4 + rr;
        const float qv = qa[(b * NSl + i) * HH + h];
        const float* e_row = e_log + (((b * HH + h) * NSl) + i) * NSl;

        float lg[2];
        bool valid[2];
        #pragma unroll
        for (int s = 0; s < 2; ++s) {
            int j = 1 + lane + 64 * s;
            bool v = (j < NSl) && !(i >= 1 && j == i);
            float l = -1e30f;
            if (v) {
                l = e_row[j] + qv + kal[j] + abv;
                if (i >= 1) {
                    float p = mask_M[((b * HH + h) * SS + (i - 1)) * SS + (j - 1)];
                    p = fminf(fmaxf(p, 1e-6f), 1.0f - 1e-6f);
                    l += __logf(p) - __logf(1.0f - p);
                }
            }
            lg[s] = l;
            valid[s] = v;
        }
        float m = fmaxf(lg[0], lg[1]);
        #pragma unroll
        for (int off = 32; off; off >>= 1) m = fmaxf(m, __shfl_xor(m, off));
        float e0 = valid[0] ? __expf(lg[0] - m) : 0.f;
        float e1 = valid[1] ? __expf(lg[1] - m) : 0.f;
        float s = e0 + e1;
        #pragma unroll
        for (int off = 32; off; off >>= 1) s += __shfl_xor(s, off);
        const float inv = 1.0f / s;

        const float p0 = e0 * inv, p1 = e1 * inv;

        float* attn_row = out + BB * NSl * HH * HDl + (((b * HH + h) * NSl) + i) * NSl;
        attn_row[1 + lane] = p0;
        if (65 + lane < NSl) attn_row[65 + lane] = p1;
        if (lane == 0) attn_row[0] = 0.f;

        pl[w][1 + lane] = p0;
        if (65 + lane < NSl) pl[w][65 + lane] = p1;
        if (lane == 0) pl[w][0] = 0.f;
        __syncthreads();

        float c0 = 0.f, c1 = 0.f, c2 = 0.f, c3 = 0.f;
        #pragma unroll 4
        for (int j = 0; j < NSl; j += 4) {
            c0 += pl[w][j]     * Vl[(j)     * HDl + lane];
            c1 += pl[w][j + 1] * Vl[(j + 1) * HDl + lane];
            c2 += pl[w][j + 2] * Vl[(j + 2) * HDl + lane];
            c3 += pl[w][j + 3] * Vl[(j + 3) * HDl + lane];
        }
        out[((b * NSl + i) * HH + h) * HDl + lane] = (c0 + c1) + (c2 + c3);
        __syncthreads();
    }
}

// ---------------------------------------------------------------------------
extern "C" void kernel_launch(void* const* d_in, const int* in_sizes, int n_in,
                              void* d_out, int out_size, void* d_ws, size_t ws_size,
                              hipStream_t stream) {
    const float* desc   = (const float*)d_in[0];
    const float* nve    = (const float*)d_in[1];
    const float* mask_M = (const float*)d_in[2];
    const float* Wq     = (const float*)d_in[3];
    const float* bq     = (const float*)d_in[4];
    const float* Wk     = (const float*)d_in[5];
    const float* bk     = (const float*)d_in[6];
    const float* Wv     = (const float*)d_in[7];
    const float* bv     = (const float*)d_in[8];
    const float* eW1    = (const float*)d_in[9];
    const float* eb1    = (const float*)d_in[10];
    const float* ln_g   = (const float*)d_in[11];
    const float* ln_b   = (const float*)d_in[12];
    const float* eW2    = (const float*)d_in[13];
    const float* eb2    = (const float*)d_in[14];
    const float* aW     = (const float*)d_in[15];
    const float* ab     = (const float*)d_in[16];

    float* ws  = (float*)d_ws;
    float* out = (float*)d_out;
    unsigned short* W2Bu = (unsigned short*)(ws + OFF_W2B);

    mega1<<<NB_PQ + NB_V + NB_FOLD, 512, 0, stream>>>(
        desc, nve, eW1, Wv, bv, eb1,
        Wq, Wk, eW2, bq, bk, eb2, aW,
        ws + OFF_P, ws + OFF_Q, ws + OFF_V,
        W2Bu, ws + OFF_WQA, ws + OFF_WKA, ws + OFF_BF);

    statqk_kernel<<<(BB * SS * 2 + BB * NSl * HH * 2 + 3) / 4, 256, 0, stream>>>(
        ws + OFF_P, ws + OFF_Q, nve, ws + OFF_WQA, ws + OFF_WKA, ws + OFF_BF,
        ws + OFF_SP, ws + OFF_SSP, ws + OFF_SQ, ws + OFF_SSQ,
        ws + OFF_QA, ws + OFF_KA);

    pair_mfma<<<dim3(8, 8, BB), 512, 0, stream>>>(
        ws + OFF_P, ws + OFF_Q, ln_g, ln_b, W2Bu,
        ws + OFF_SP, ws + OFF_SSP, ws + OFF_SQ, ws + OFF_SSQ,
        ws + OFF_BF, ws + OFF_EL);

    softmax_ctx_kernel<<<dim3(4, HH, BB), 512, 0, stream>>>(
        ws + OFF_EL, ws + OFF_QA, ws + OFF_KA, mask_M, ab, ws + OFF_V, out);
}